// Round 4
// baseline (394.896 us; speedup 1.0000x reference)
//
#include <hip/hip_runtime.h>

typedef __attribute__((ext_vector_type(8))) short bf16x8;
typedef __attribute__((ext_vector_type(4))) float floatx4;

#define B_    4
#define N_    2048
#define DIM_  512
#define NH_   8
#define HD_   64
#define SCALE_ 0.125f

__device__ __forceinline__ unsigned short f32_to_bf16(float f) {
    unsigned int u = __float_as_uint(f);
    u += 0x7FFFu + ((u >> 16) & 1u);   // round-to-nearest-even
    return (unsigned short)(u >> 16);
}

__device__ __forceinline__ floatx4 mfma16(bf16x8 a, bf16x8 b, floatx4 c) {
    return __builtin_amdgcn_mfma_f32_16x16x32_bf16(a, b, c, 0, 0, 0);
}

__device__ __forceinline__ floatx4 fzero4() {
    floatx4 z = {0.f, 0.f, 0.f, 0.f};
    return z;
}

// ---------------- LayerNorm: x[8192][512] fp32 -> xn bf16 ----------------
__global__ __launch_bounds__(256) void ln_kernel(const float* __restrict__ x,
                                                 const float* __restrict__ w,
                                                 const float* __restrict__ b,
                                                 unsigned short* __restrict__ xn) {
    int row = blockIdx.x;
    int tid = threadIdx.x;
    int lane = tid & 63, wid = tid >> 6;
    const float2 v = ((const float2*)(x + (size_t)row * DIM_))[tid];
    float s = v.x + v.y;
    float sq = v.x * v.x + v.y * v.y;
#pragma unroll
    for (int off = 1; off < 64; off <<= 1) {
        s  += __shfl_xor(s, off, 64);
        sq += __shfl_xor(sq, off, 64);
    }
    __shared__ float red[2][4];
    if (lane == 0) { red[0][wid] = s; red[1][wid] = sq; }
    __syncthreads();
    s  = red[0][0] + red[0][1] + red[0][2] + red[0][3];
    sq = red[1][0] + red[1][1] + red[1][2] + red[1][3];
    float mu   = s * (1.f / DIM_);
    float var  = sq * (1.f / DIM_) - mu * mu;
    float rstd = rsqrtf(var + 1e-5f);
    float2 wv = ((const float2*)w)[tid];
    float2 bv = ((const float2*)b)[tid];
    float y0 = (v.x - mu) * rstd * wv.x + bv.x;
    float y1 = (v.y - mu) * rstd * wv.y + bv.y;
    unsigned int pack = (unsigned int)f32_to_bf16(y0) |
                        ((unsigned int)f32_to_bf16(y1) << 16);
    ((unsigned int*)xn)[(size_t)row * (DIM_ / 2) + tid] = pack;
}

// ---------------- fp32 -> bf16 convert (both weight matrices, one launch) ----------------
__global__ __launch_bounds__(256) void cvt_kernel(const float* __restrict__ srcA, int na,
                                                  const float* __restrict__ srcB, int nb,
                                                  unsigned short* __restrict__ dstA,
                                                  unsigned short* __restrict__ dstB) {
    int idx = blockIdx.x * 256 + threadIdx.x;
    if (idx < na)            dstA[idx] = f32_to_bf16(srcA[idx]);
    else if (idx < na + nb)  dstB[idx - na] = f32_to_bf16(srcB[idx - na]);
}

// ---------------- QKV GEMM: [8192,512] x [1536,512]^T, scatter epilogue ----------------
__global__ __launch_bounds__(256) void qkv_gemm(const unsigned short* __restrict__ A,
                                                const unsigned short* __restrict__ Bw,
                                                const float* __restrict__ bias,
                                                unsigned short* __restrict__ Qh,
                                                unsigned short* __restrict__ Kh,
                                                unsigned short* __restrict__ Vt) {
    int tid = threadIdx.x, lane = tid & 63, wid = tid >> 6;
    int l15 = lane & 15, quad = lane >> 4;
    int wm = blockIdx.x * 128 + (wid >> 1) * 64;
    int wn = blockIdx.y * 128 + (wid & 1) * 64;

    floatx4 acc[4][4];
#pragma unroll
    for (int i = 0; i < 4; i++)
#pragma unroll
        for (int j = 0; j < 4; j++) acc[i][j] = fzero4();

    const bf16x8* aptr[4];
    const bf16x8* bptr[4];
#pragma unroll
    for (int i = 0; i < 4; i++)
        aptr[i] = (const bf16x8*)(A + (size_t)(wm + 16 * i + l15) * DIM_ + quad * 8);
#pragma unroll
    for (int j = 0; j < 4; j++)
        bptr[j] = (const bf16x8*)(Bw + (size_t)(wn + 16 * j + l15) * DIM_ + quad * 8);

    for (int k = 0; k < DIM_; k += 32) {
        bf16x8 av[4], bv[4];
        int kk = k >> 3;
#pragma unroll
        for (int i = 0; i < 4; i++) av[i] = aptr[i][kk];
#pragma unroll
        for (int j = 0; j < 4; j++) bv[j] = bptr[j][kk];
#pragma unroll
        for (int i = 0; i < 4; i++)
#pragma unroll
            for (int j = 0; j < 4; j++)
                acc[i][j] = mfma16(av[i], bv[j], acc[i][j]);
    }

#pragma unroll
    for (int i = 0; i < 4; i++) {
#pragma unroll
        for (int j = 0; j < 4; j++) {
            int n = wn + 16 * j + l15;
            float bias_n = bias[n];
            int which = n >> 9;
            int rem = n & 511;
            int head = rem >> 6;
            int d = rem & 63;
#pragma unroll
            for (int r = 0; r < 4; r++) {
                int m = wm + 16 * i + quad * 4 + r;
                int b = m >> 11;
                int t = m & 2047;
                unsigned short h16 = f32_to_bf16(acc[i][j][r] + bias_n);
                if (which == 0)
                    Qh[((size_t)(b * NH_ + head) * N_ + t) * HD_ + d] = h16;
                else if (which == 1)
                    Kh[((size_t)(b * NH_ + head) * N_ + t) * HD_ + d] = h16;
                else
                    Vt[((size_t)(b * NH_ + head) * HD_ + d) * N_ + t] = h16;
            }
        }
    }
}

// ---------------- Flash attention, fixed-max softmax, register-pipelined ----------------
// grid (32 qtiles, 32 bh), block 256 = 4 waves x 16 q-rows, KV steps of 64.
// K fragments double-buffered in VGPRs (prefetch next iter at top of current);
// V fragments issued at iteration top, consumed after QK+softmax+LDS roundtrip.
// Manual 2x unroll so the K-buffer swap is register renaming.
// NOTE: final K prefetch reads <=8KB past Kh's end -> lands inside Vt (valid
// device memory, values discarded). Workspace ordering guarantees this.
__global__ __launch_bounds__(256) void attn_kernel(const unsigned short* __restrict__ Qh,
                                                   const unsigned short* __restrict__ Kh,
                                                   const unsigned short* __restrict__ Vt,
                                                   unsigned short* __restrict__ Obuf) {
    int bh = blockIdx.y;
    int b = bh >> 3, head = bh & 7;
    int qt = blockIdx.x;
    int tid = threadIdx.x, lane = tid & 63, w = tid >> 6;
    int l15 = lane & 15, quad = lane >> 4;

    const unsigned short* Qp = Qh + (size_t)bh * N_ * HD_;
    const unsigned short* Krow = Kh + (size_t)bh * N_ * HD_ + (size_t)l15 * HD_ + quad * 8;
    const unsigned short* Vrow = Vt + (size_t)bh * HD_ * N_ + (size_t)l15 * N_ + quad * 8;

    int q0 = qt * 64 + w * 16;

    bf16x8 aQ0 = *(const bf16x8*)(Qp + (size_t)(q0 + l15) * HD_ + quad * 8);
    bf16x8 aQ1 = *(const bf16x8*)(Qp + (size_t)(q0 + l15) * HD_ + 32 + quad * 8);

    floatx4 of[4];
#pragma unroll
    for (int t = 0; t < 4; t++) of[t] = fzero4();
    floatx4 lacc = fzero4();

    const short onebf = (short)0x3F80;   // bf16 1.0
    bf16x8 ones = {onebf, onebf, onebf, onebf, onebf, onebf, onebf, onebf};

    const float SL2E = SCALE_ * 1.44269504f;   // scale * log2(e)

    __shared__ unsigned short Pl[2][4][16][72];  // double-buffered, wave-private, padded

#define LOADK(arr, KV)                                                          \
    _Pragma("unroll")                                                           \
    for (int h = 0; h < 4; h++) {                                               \
        arr[2*h]   = *(const bf16x8*)(Krow + (size_t)((KV) + 16*h) * HD_);      \
        arr[2*h+1] = *(const bf16x8*)(Krow + (size_t)((KV) + 16*h) * HD_ + 32); \
    }

#define STEP(KV, CUR, NXT)                                                        \
    {                                                                             \
        bf16x8 vf[8];                                                             \
        _Pragma("unroll")                                                         \
        for (int t = 0; t < 4; t++) {                                             \
            vf[2*t]   = *(const bf16x8*)(Vrow + (size_t)(16*t) * N_ + (KV));      \
            vf[2*t+1] = *(const bf16x8*)(Vrow + (size_t)(16*t) * N_ + (KV) + 32); \
        }                                                                         \
        LOADK(NXT, (KV) + 64);                                                    \
        floatx4 c[4];                                                             \
        _Pragma("unroll")                                                         \
        for (int h = 0; h < 4; h++) {                                             \
            floatx4 cc = fzero4();                                                \
            cc = mfma16(aQ0, CUR[2*h], cc);                                       \
            cc = mfma16(aQ1, CUR[2*h+1], cc);                                     \
            c[h] = cc;                                                            \
        }                                                                         \
        unsigned short* myP = &Pl[((KV) >> 6) & 1][w][0][0];                      \
        _Pragma("unroll")                                                         \
        for (int h = 0; h < 4; h++)                                               \
            _Pragma("unroll")                                                     \
            for (int r = 0; r < 4; r++)                                           \
                myP[(quad*4 + r)*72 + h*16 + l15] =                               \
                    f32_to_bf16(exp2f(c[h][r] * SL2E));                           \
        bf16x8 aP0 = *(const bf16x8*)(myP + l15*72 + quad*8);                     \
        bf16x8 aP1 = *(const bf16x8*)(myP + l15*72 + 32 + quad*8);                \
        _Pragma("unroll")                                                         \
        for (int t = 0; t < 4; t++) {                                             \
            of[t] = mfma16(aP0, vf[2*t], of[t]);                                  \
            of[t] = mfma16(aP1, vf[2*t+1], of[t]);                                \
        }                                                                         \
        lacc = mfma16(aP0, ones, lacc);                                           \
        lacc = mfma16(aP1, ones, lacc);                                           \
    }

    bf16x8 ka[8], kb[8];
    LOADK(ka, 0);
    for (int kv = 0; kv < N_; kv += 128) {
        STEP(kv,      ka, kb);
        STEP(kv + 64, kb, ka);
    }
#undef STEP
#undef LOADK

    float inv[4];
#pragma unroll
    for (int r = 0; r < 4; r++) inv[r] = 1.f / lacc[r];
#pragma unroll
    for (int t = 0; t < 4; t++) {
#pragma unroll
        for (int r = 0; r < 4; r++) {
            int t_tok = q0 + quad * 4 + r;
            int d = 16 * t + l15;
            Obuf[((size_t)b * N_ + t_tok) * DIM_ + head * HD_ + d] =
                f32_to_bf16(of[t][r] * inv[r]);
        }
    }
}

// ---------------- Out projection: [8192,512] x [512,512]^T + bias -> fp32 ----------------
__global__ __launch_bounds__(256) void out_gemm(const unsigned short* __restrict__ A,
                                                const unsigned short* __restrict__ Bw,
                                                const float* __restrict__ bias,
                                                float* __restrict__ out) {
    int tid = threadIdx.x, lane = tid & 63, wid = tid >> 6;
    int l15 = lane & 15, quad = lane >> 4;
    int wm = blockIdx.x * 128 + (wid >> 1) * 64;
    int wn = blockIdx.y * 128 + (wid & 1) * 64;

    floatx4 acc[4][4];
#pragma unroll
    for (int i = 0; i < 4; i++)
#pragma unroll
        for (int j = 0; j < 4; j++) acc[i][j] = fzero4();

    const bf16x8* aptr[4];
    const bf16x8* bptr[4];
#pragma unroll
    for (int i = 0; i < 4; i++)
        aptr[i] = (const bf16x8*)(A + (size_t)(wm + 16 * i + l15) * DIM_ + quad * 8);
#pragma unroll
    for (int j = 0; j < 4; j++)
        bptr[j] = (const bf16x8*)(Bw + (size_t)(wn + 16 * j + l15) * DIM_ + quad * 8);

    for (int k = 0; k < DIM_; k += 32) {
        bf16x8 av[4], bv[4];
        int kk = k >> 3;
#pragma unroll
        for (int i = 0; i < 4; i++) av[i] = aptr[i][kk];
#pragma unroll
        for (int j = 0; j < 4; j++) bv[j] = bptr[j][kk];
#pragma unroll
        for (int i = 0; i < 4; i++)
#pragma unroll
            for (int j = 0; j < 4; j++)
                acc[i][j] = mfma16(av[i], bv[j], acc[i][j]);
    }

#pragma unroll
    for (int i = 0; i < 4; i++) {
#pragma unroll
        for (int j = 0; j < 4; j++) {
            int n = wn + 16 * j + l15;
            float bias_n = bias[n];
#pragma unroll
            for (int r = 0; r < 4; r++) {
                int m = wm + 16 * i + quad * 4 + r;
                out[(size_t)m * DIM_ + n] = acc[i][j][r] + bias_n;
            }
        }
    }
}

extern "C" void kernel_launch(void* const* d_in, const int* in_sizes, int n_in,
                              void* d_out, int out_size, void* d_ws, size_t ws_size,
                              hipStream_t stream) {
    const float* x     = (const float*)d_in[0];
    const float* ln_w  = (const float*)d_in[1];
    const float* ln_b  = (const float*)d_in[2];
    const float* qkv_w = (const float*)d_in[3];
    const float* qkv_b = (const float*)d_in[4];
    const float* out_w = (const float*)d_in[5];
    const float* out_b = (const float*)d_in[6];
    float* out = (float*)d_out;

    char* ws = (char*)d_ws;
    const size_t TOK = (size_t)B_ * N_;                 // 8192
    unsigned short* xn    = (unsigned short*)ws;  ws += TOK * DIM_ * 2;
    unsigned short* wq_bf = (unsigned short*)ws;  ws += (size_t)3 * DIM_ * DIM_ * 2;
    unsigned short* wo_bf = (unsigned short*)ws;  ws += (size_t)DIM_ * DIM_ * 2;
    unsigned short* Qh    = (unsigned short*)ws;  ws += TOK * DIM_ * 2;
    unsigned short* Kh    = (unsigned short*)ws;  ws += TOK * DIM_ * 2;   // Vt MUST follow Kh (prefetch overrun pad)
    unsigned short* Vt    = (unsigned short*)ws;  ws += TOK * DIM_ * 2;
    unsigned short* Obuf  = (unsigned short*)ws;  ws += TOK * DIM_ * 2;

    const int NW = 3 * DIM_ * DIM_;      // qkv_w elements
    const int NO = DIM_ * DIM_;          // out_w elements

    ln_kernel<<<TOK, 256, 0, stream>>>(x, ln_w, ln_b, xn);
    cvt_kernel<<<(NW + NO + 255) / 256, 256, 0, stream>>>(qkv_w, NW, out_w, NO, wq_bf, wo_bf);
    qkv_gemm<<<dim3(TOK / 128, (3 * DIM_) / 128), 256, 0, stream>>>(xn, wq_bf, qkv_b, Qh, Kh, Vt);
    attn_kernel<<<dim3(N_ / 64, B_ * NH_), 256, 0, stream>>>(Qh, Kh, Vt, Obuf);
    out_gemm<<<dim3(TOK / 128, DIM_ / 128), 256, 0, stream>>>(Obuf, wo_bf, out_b, out);
}

// Round 5
// 236.416 us; speedup vs baseline: 1.6703x; 1.6703x over previous
//
#include <hip/hip_runtime.h>

typedef __attribute__((ext_vector_type(8))) short bf16x8;
typedef __attribute__((ext_vector_type(4))) float floatx4;

#define B_    4
#define N_    2048
#define DIM_  512
#define NH_   8
#define HD_   64
#define SCALE_ 0.125f

__device__ __forceinline__ unsigned short f32_to_bf16(float f) {
    unsigned int u = __float_as_uint(f);
    u += 0x7FFFu + ((u >> 16) & 1u);   // round-to-nearest-even
    return (unsigned short)(u >> 16);
}

__device__ __forceinline__ floatx4 mfma16(bf16x8 a, bf16x8 b, floatx4 c) {
    return __builtin_amdgcn_mfma_f32_16x16x32_bf16(a, b, c, 0, 0, 0);
}

__device__ __forceinline__ floatx4 fzero4() {
    floatx4 z = {0.f, 0.f, 0.f, 0.f};
    return z;
}

// async global->LDS DMA, 16B per lane. lds dest is wave-uniform base; HW adds lane*16.
__device__ __forceinline__ void async16(const unsigned short* g, unsigned short* l) {
    __builtin_amdgcn_global_load_lds((const __attribute__((address_space(1))) void*)g,
                                     (__attribute__((address_space(3))) void*)l,
                                     16, 0, 0);
}

// ---------------- LayerNorm: x[8192][512] fp32 -> xn bf16 ----------------
__global__ __launch_bounds__(256) void ln_kernel(const float* __restrict__ x,
                                                 const float* __restrict__ w,
                                                 const float* __restrict__ b,
                                                 unsigned short* __restrict__ xn) {
    int row = blockIdx.x;
    int tid = threadIdx.x;
    int lane = tid & 63, wid = tid >> 6;
    const float2 v = ((const float2*)(x + (size_t)row * DIM_))[tid];
    float s = v.x + v.y;
    float sq = v.x * v.x + v.y * v.y;
#pragma unroll
    for (int off = 1; off < 64; off <<= 1) {
        s  += __shfl_xor(s, off, 64);
        sq += __shfl_xor(sq, off, 64);
    }
    __shared__ float red[2][4];
    if (lane == 0) { red[0][wid] = s; red[1][wid] = sq; }
    __syncthreads();
    s  = red[0][0] + red[0][1] + red[0][2] + red[0][3];
    sq = red[1][0] + red[1][1] + red[1][2] + red[1][3];
    float mu   = s * (1.f / DIM_);
    float var  = sq * (1.f / DIM_) - mu * mu;
    float rstd = rsqrtf(var + 1e-5f);
    float2 wv = ((const float2*)w)[tid];
    float2 bv = ((const float2*)b)[tid];
    float y0 = (v.x - mu) * rstd * wv.x + bv.x;
    float y1 = (v.y - mu) * rstd * wv.y + bv.y;
    unsigned int pack = (unsigned int)f32_to_bf16(y0) |
                        ((unsigned int)f32_to_bf16(y1) << 16);
    ((unsigned int*)xn)[(size_t)row * (DIM_ / 2) + tid] = pack;
}

// ---------------- fp32 -> bf16 convert (both weight matrices, one launch) ----------------
__global__ __launch_bounds__(256) void cvt_kernel(const float* __restrict__ srcA, int na,
                                                  const float* __restrict__ srcB, int nb,
                                                  unsigned short* __restrict__ dstA,
                                                  unsigned short* __restrict__ dstB) {
    int idx = blockIdx.x * 256 + threadIdx.x;
    if (idx < na)            dstA[idx] = f32_to_bf16(srcA[idx]);
    else if (idx < na + nb)  dstB[idx - na] = f32_to_bf16(srcB[idx - na]);
}

// ---------------- QKV GEMM: [8192,512] x [1536,512]^T, scatter epilogue ----------------
__global__ __launch_bounds__(256) void qkv_gemm(const unsigned short* __restrict__ A,
                                                const unsigned short* __restrict__ Bw,
                                                const float* __restrict__ bias,
                                                unsigned short* __restrict__ Qh,
                                                unsigned short* __restrict__ Kh,
                                                unsigned short* __restrict__ Vt) {
    int tid = threadIdx.x, lane = tid & 63, wid = tid >> 6;
    int l15 = lane & 15, quad = lane >> 4;
    int wm = blockIdx.x * 128 + (wid >> 1) * 64;
    int wn = blockIdx.y * 128 + (wid & 1) * 64;

    floatx4 acc[4][4];
#pragma unroll
    for (int i = 0; i < 4; i++)
#pragma unroll
        for (int j = 0; j < 4; j++) acc[i][j] = fzero4();

    const bf16x8* aptr[4];
    const bf16x8* bptr[4];
#pragma unroll
    for (int i = 0; i < 4; i++)
        aptr[i] = (const bf16x8*)(A + (size_t)(wm + 16 * i + l15) * DIM_ + quad * 8);
#pragma unroll
    for (int j = 0; j < 4; j++)
        bptr[j] = (const bf16x8*)(Bw + (size_t)(wn + 16 * j + l15) * DIM_ + quad * 8);

    for (int k = 0; k < DIM_; k += 32) {
        bf16x8 av[4], bv[4];
        int kk = k >> 3;
#pragma unroll
        for (int i = 0; i < 4; i++) av[i] = aptr[i][kk];
#pragma unroll
        for (int j = 0; j < 4; j++) bv[j] = bptr[j][kk];
#pragma unroll
        for (int i = 0; i < 4; i++)
#pragma unroll
            for (int j = 0; j < 4; j++)
                acc[i][j] = mfma16(av[i], bv[j], acc[i][j]);
    }

#pragma unroll
    for (int i = 0; i < 4; i++) {
#pragma unroll
        for (int j = 0; j < 4; j++) {
            int n = wn + 16 * j + l15;
            float bias_n = bias[n];
            int which = n >> 9;
            int rem = n & 511;
            int head = rem >> 6;
            int d = rem & 63;
#pragma unroll
            for (int r = 0; r < 4; r++) {
                int m = wm + 16 * i + quad * 4 + r;
                int b = m >> 11;
                int t = m & 2047;
                unsigned short h16 = f32_to_bf16(acc[i][j][r] + bias_n);
                if (which == 0)
                    Qh[((size_t)(b * NH_ + head) * N_ + t) * HD_ + d] = h16;
                else if (which == 1)
                    Kh[((size_t)(b * NH_ + head) * N_ + t) * HD_ + d] = h16;
                else
                    Vt[((size_t)(b * NH_ + head) * HD_ + d) * N_ + t] = h16;
            }
        }
    }
}

// ---------------- Flash attention, fixed-max softmax, LDS-staged K/V ----------------
// grid (32 qtiles, 32 bh), block 256 = 4 waves x 16 q-rows, KV steps of 64.
// K/V tiles staged in LDS via global_load_lds (async DMA), double-buffered,
// shared by all 4 waves (4x L2-traffic dedupe). XOR swizzle (slot u holds
// global unit u^(row&7)) replaces padding since global_load_lds scatters
// lane*16B from a wave-uniform base. One __syncthreads per iteration; its
// vmcnt drain lands after the full compute window.
// launch_bounds(256,4): 128-VGPR budget, 4 blocks/CU (LDS 40KB exactly fits 4).
__global__ __launch_bounds__(256, 4) void attn_kernel(const unsigned short* __restrict__ Qh,
                                                      const unsigned short* __restrict__ Kh,
                                                      const unsigned short* __restrict__ Vtg,
                                                      unsigned short* __restrict__ Obuf) {
    int bh = blockIdx.y;
    int b = bh >> 3, head = bh & 7;
    int qt = blockIdx.x;
    int tid = threadIdx.x, lane = tid & 63, w = tid >> 6;
    int l15 = lane & 15, quad = lane >> 4;

    const unsigned short* Qp = Qh + (size_t)bh * N_ * HD_;
    const unsigned short* Kg = Kh + (size_t)bh * N_ * HD_;
    const unsigned short* Vg = Vtg + (size_t)bh * HD_ * N_;

    int q0 = qt * 64 + w * 16;

    bf16x8 aQ0 = *(const bf16x8*)(Qp + (size_t)(q0 + l15) * HD_ + quad * 8);
    bf16x8 aQ1 = *(const bf16x8*)(Qp + (size_t)(q0 + l15) * HD_ + 32 + quad * 8);

    floatx4 of[4];
#pragma unroll
    for (int t = 0; t < 4; t++) of[t] = fzero4();
    floatx4 lacc = fzero4();

    const short onebf = (short)0x3F80;   // bf16 1.0
    bf16x8 ones = {onebf, onebf, onebf, onebf, onebf, onebf, onebf, onebf};

    const float SL2E = SCALE_ * 1.44269504f;   // scale * log2(e)

    __shared__ unsigned short Kt[2][64][64];   // 16 KB  [kv-row][d-unit swizzled]
    __shared__ unsigned short Vs[2][64][64];   // 16 KB  [d-row][kv-unit swizzled]
    __shared__ unsigned short Pl[4][16][64];   //  8 KB  wave-private, swizzled

    // staging geometry: lane l fetches global unit (l&7)^(l>>3) of row base+ (l>>3)
    int srow = lane >> 3;                 // 0..7
    int scol = ((lane & 7) ^ srow) * 8;   // shorts

#define STAGE(BUF, KV)                                                              \
    {                                                                               \
        _Pragma("unroll")                                                           \
        for (int i = 0; i < 2; i++) {                                               \
            int r0 = 16 * w + 8 * i;                                                \
            async16(Kg + (size_t)((KV) + r0 + srow) * HD_ + scol, &Kt[BUF][r0][0]); \
            async16(Vg + (size_t)(r0 + srow) * N_ + (KV) + scol, &Vs[BUF][r0][0]);  \
        }                                                                           \
    }

    STAGE(0, 0);
    __syncthreads();

    unsigned short* myP = &Pl[w][0][0];
    int buf = 0;
    for (int kv = 0; kv < N_; kv += 64) {
        if (kv + 64 < N_) STAGE(buf ^ 1, kv + 64);
        // ---- S = Q K^T : B-frag rows from swizzled LDS ----
        floatx4 c[4];
#pragma unroll
        for (int h = 0; h < 4; h++) {
            int krow = 16 * h + l15;
            int sw = l15 & 7;
            bf16x8 b0 = *(const bf16x8*)(&Kt[buf][krow][(quad ^ sw) * 8]);
            bf16x8 b1 = *(const bf16x8*)(&Kt[buf][krow][((quad + 4) ^ sw) * 8]);
            floatx4 cc = fzero4();
            cc = mfma16(aQ0, b0, cc);
            cc = mfma16(aQ1, b1, cc);
            c[h] = cc;
        }
        // ---- P = exp2(S*scale*log2e) -> LDS (C layout, swizzled) ----
#pragma unroll
        for (int h = 0; h < 4; h++)
#pragma unroll
            for (int r = 0; r < 4; r++) {
                int prow = quad * 4 + r;
                int unit = 2 * h + (l15 >> 3);
                myP[prow * 64 + ((unit ^ (prow & 7)) * 8) + (l15 & 7)] =
                    f32_to_bf16(exp2f(c[h][r] * SL2E));
            }
        // ---- read P back as A-fragments ----
        {
            int sw = l15 & 7;
            bf16x8 aP0 = *(const bf16x8*)(myP + l15 * 64 + (quad ^ sw) * 8);
            bf16x8 aP1 = *(const bf16x8*)(myP + l15 * 64 + ((quad + 4) ^ sw) * 8);
            // ---- O += P V ; l += P * ones ----
#pragma unroll
            for (int t = 0; t < 4; t++) {
                int vrow = 16 * t + l15;
                bf16x8 v0 = *(const bf16x8*)(&Vs[buf][vrow][(quad ^ sw) * 8]);
                bf16x8 v1 = *(const bf16x8*)(&Vs[buf][vrow][((quad + 4) ^ sw) * 8]);
                of[t] = mfma16(aP0, v0, of[t]);
                of[t] = mfma16(aP1, v1, of[t]);
            }
            lacc = mfma16(aP0, ones, lacc);
            lacc = mfma16(aP1, ones, lacc);
        }
        __syncthreads();
        buf ^= 1;
    }
#undef STAGE

    float inv[4];
#pragma unroll
    for (int r = 0; r < 4; r++) inv[r] = 1.f / lacc[r];
#pragma unroll
    for (int t = 0; t < 4; t++) {
#pragma unroll
        for (int r = 0; r < 4; r++) {
            int t_tok = q0 + quad * 4 + r;
            int d = 16 * t + l15;
            Obuf[((size_t)b * N_ + t_tok) * DIM_ + head * HD_ + d] =
                f32_to_bf16(of[t][r] * inv[r]);
        }
    }
}

// ---------------- Out projection: [8192,512] x [512,512]^T + bias -> fp32 ----------------
__global__ __launch_bounds__(256) void out_gemm(const unsigned short* __restrict__ A,
                                                const unsigned short* __restrict__ Bw,
                                                const float* __restrict__ bias,
                                                float* __restrict__ out) {
    int tid = threadIdx.x, lane = tid & 63, wid = tid >> 6;
    int l15 = lane & 15, quad = lane >> 4;
    int wm = blockIdx.x * 128 + (wid >> 1) * 64;
    int wn = blockIdx.y * 128 + (wid & 1) * 64;

    floatx4 acc[4][4];
#pragma unroll
    for (int i = 0; i < 4; i++)
#pragma unroll
        for (int j = 0; j < 4; j++) acc[i][j] = fzero4();

    const bf16x8* aptr[4];
    const bf16x8* bptr[4];
#pragma unroll
    for (int i = 0; i < 4; i++)
        aptr[i] = (const bf16x8*)(A + (size_t)(wm + 16 * i + l15) * DIM_ + quad * 8);
#pragma unroll
    for (int j = 0; j < 4; j++)
        bptr[j] = (const bf16x8*)(Bw + (size_t)(wn + 16 * j + l15) * DIM_ + quad * 8);

    for (int k = 0; k < DIM_; k += 32) {
        bf16x8 av[4], bv[4];
        int kk = k >> 3;
#pragma unroll
        for (int i = 0; i < 4; i++) av[i] = aptr[i][kk];
#pragma unroll
        for (int j = 0; j < 4; j++) bv[j] = bptr[j][kk];
#pragma unroll
        for (int i = 0; i < 4; i++)
#pragma unroll
            for (int j = 0; j < 4; j++)
                acc[i][j] = mfma16(av[i], bv[j], acc[i][j]);
    }

#pragma unroll
    for (int i = 0; i < 4; i++) {
#pragma unroll
        for (int j = 0; j < 4; j++) {
            int n = wn + 16 * j + l15;
            float bias_n = bias[n];
#pragma unroll
            for (int r = 0; r < 4; r++) {
                int m = wm + 16 * i + quad * 4 + r;
                out[(size_t)m * DIM_ + n] = acc[i][j][r] + bias_n;
            }
        }
    }
}

extern "C" void kernel_launch(void* const* d_in, const int* in_sizes, int n_in,
                              void* d_out, int out_size, void* d_ws, size_t ws_size,
                              hipStream_t stream) {
    const float* x     = (const float*)d_in[0];
    const float* ln_w  = (const float*)d_in[1];
    const float* ln_b  = (const float*)d_in[2];
    const float* qkv_w = (const float*)d_in[3];
    const float* qkv_b = (const float*)d_in[4];
    const float* out_w = (const float*)d_in[5];
    const float* out_b = (const float*)d_in[6];
    float* out = (float*)d_out;

    char* ws = (char*)d_ws;
    const size_t TOK = (size_t)B_ * N_;                 // 8192
    unsigned short* xn    = (unsigned short*)ws;  ws += TOK * DIM_ * 2;
    unsigned short* wq_bf = (unsigned short*)ws;  ws += (size_t)3 * DIM_ * DIM_ * 2;
    unsigned short* wo_bf = (unsigned short*)ws;  ws += (size_t)DIM_ * DIM_ * 2;
    unsigned short* Qh    = (unsigned short*)ws;  ws += TOK * DIM_ * 2;
    unsigned short* Kh    = (unsigned short*)ws;  ws += TOK * DIM_ * 2;
    unsigned short* Vt    = (unsigned short*)ws;  ws += TOK * DIM_ * 2;
    unsigned short* Obuf  = (unsigned short*)ws;  ws += TOK * DIM_ * 2;

    const int NW = 3 * DIM_ * DIM_;      // qkv_w elements
    const int NO = DIM_ * DIM_;          // out_w elements

    ln_kernel<<<TOK, 256, 0, stream>>>(x, ln_w, ln_b, xn);
    cvt_kernel<<<(NW + NO + 255) / 256, 256, 0, stream>>>(qkv_w, NW, out_w, NO, wq_bf, wo_bf);
    qkv_gemm<<<dim3(TOK / 128, (3 * DIM_) / 128), 256, 0, stream>>>(xn, wq_bf, qkv_b, Qh, Kh, Vt);
    attn_kernel<<<dim3(N_ / 64, B_ * NH_), 256, 0, stream>>>(Qh, Kh, Vt, Obuf);
    out_gemm<<<dim3(TOK / 128, DIM_ / 128), 256, 0, stream>>>(Obuf, wo_bf, out_b, out);
}

// Round 6
// 193.374 us; speedup vs baseline: 2.0421x; 1.2226x over previous
//
#include <hip/hip_runtime.h>

typedef __attribute__((ext_vector_type(8))) short bf16x8;
typedef __attribute__((ext_vector_type(4))) float floatx4;

#define B_    4
#define N_    2048
#define DIM_  512
#define NH_   8
#define HD_   64
#define SCALE_ 0.125f

__device__ __forceinline__ unsigned short f32_to_bf16(float f) {
    unsigned int u = __float_as_uint(f);
    u += 0x7FFFu + ((u >> 16) & 1u);   // round-to-nearest-even
    return (unsigned short)(u >> 16);
}

__device__ __forceinline__ floatx4 mfma16(bf16x8 a, bf16x8 b, floatx4 c) {
    return __builtin_amdgcn_mfma_f32_16x16x32_bf16(a, b, c, 0, 0, 0);
}

__device__ __forceinline__ floatx4 fzero4() {
    floatx4 z = {0.f, 0.f, 0.f, 0.f};
    return z;
}

// async global->LDS DMA, 16B per lane. lds dest is wave-uniform base; HW adds lane*16.
__device__ __forceinline__ void async16(const unsigned short* g, unsigned short* l) {
    __builtin_amdgcn_global_load_lds((const __attribute__((address_space(1))) void*)g,
                                     (__attribute__((address_space(3))) void*)l,
                                     16, 0, 0);
}

// ---------------- LayerNorm: x[8192][512] fp32 -> xn bf16 ----------------
__global__ __launch_bounds__(256) void ln_kernel(const float* __restrict__ x,
                                                 const float* __restrict__ w,
                                                 const float* __restrict__ b,
                                                 unsigned short* __restrict__ xn) {
    int row = blockIdx.x;
    int tid = threadIdx.x;
    int lane = tid & 63, wid = tid >> 6;
    const float2 v = ((const float2*)(x + (size_t)row * DIM_))[tid];
    float s = v.x + v.y;
    float sq = v.x * v.x + v.y * v.y;
#pragma unroll
    for (int off = 1; off < 64; off <<= 1) {
        s  += __shfl_xor(s, off, 64);
        sq += __shfl_xor(sq, off, 64);
    }
    __shared__ float red[2][4];
    if (lane == 0) { red[0][wid] = s; red[1][wid] = sq; }
    __syncthreads();
    s  = red[0][0] + red[0][1] + red[0][2] + red[0][3];
    sq = red[1][0] + red[1][1] + red[1][2] + red[1][3];
    float mu   = s * (1.f / DIM_);
    float var  = sq * (1.f / DIM_) - mu * mu;
    float rstd = rsqrtf(var + 1e-5f);
    float2 wv = ((const float2*)w)[tid];
    float2 bv = ((const float2*)b)[tid];
    float y0 = (v.x - mu) * rstd * wv.x + bv.x;
    float y1 = (v.y - mu) * rstd * wv.y + bv.y;
    unsigned int pack = (unsigned int)f32_to_bf16(y0) |
                        ((unsigned int)f32_to_bf16(y1) << 16);
    ((unsigned int*)xn)[(size_t)row * (DIM_ / 2) + tid] = pack;
}

// ---------------- fp32 -> bf16 convert (both weight matrices, one launch) ----------------
__global__ __launch_bounds__(256) void cvt_kernel(const float* __restrict__ srcA, int na,
                                                  const float* __restrict__ srcB, int nb,
                                                  unsigned short* __restrict__ dstA,
                                                  unsigned short* __restrict__ dstB) {
    int idx = blockIdx.x * 256 + threadIdx.x;
    if (idx < na)            dstA[idx] = f32_to_bf16(srcA[idx]);
    else if (idx < na + nb)  dstB[idx - na] = f32_to_bf16(srcB[idx - na]);
}

// ================= m97-style LDS-staged GEMM core (shared by both GEMMs) =================
// 128x128 block tile, BK=32, double-buffered LDS, global_load_lds width=16.
// A [M][512] row-major, B [Nn][512] row-major (NT GEMM). acc[i][j] per wave 64x64.
#define GEMM_CORE(A_, B_ptr, am0, bn0)                                              \
    __shared__ unsigned short Alds[2][128][32];                                     \
    __shared__ unsigned short Blds[2][128][32];                                     \
    int tid = threadIdx.x, lane = tid & 63, wid = tid >> 6;                         \
    int l15 = lane & 15, quad = lane >> 4;                                          \
    int wmloc = (wid >> 1) * 64, wnloc = (wid & 1) * 64;                            \
    int sr = lane >> 2;            /* row 0..15 within 16-row stripe */             \
    int sc = (lane & 3) * 8;       /* k-offset in shorts */                         \
    floatx4 acc[4][4];                                                              \
    _Pragma("unroll")                                                               \
    for (int i = 0; i < 4; i++)                                                     \
        _Pragma("unroll")                                                           \
        for (int j = 0; j < 4; j++) acc[i][j] = fzero4();                           \
    int buf = 0;                                                                    \
    /* stage k-tile 0 */                                                            \
    _Pragma("unroll")                                                               \
    for (int i = 0; i < 2; i++) {                                                   \
        int r0 = 32 * wid + 16 * i;                                                 \
        async16(A_ + (size_t)(am0 + r0 + sr) * DIM_ + sc, &Alds[0][r0][0]);         \
        async16(B_ptr + (size_t)(bn0 + r0 + sr) * DIM_ + sc, &Blds[0][r0][0]);      \
    }                                                                               \
    __syncthreads();                                                                \
    for (int t = 0; t < 16; t++) {                                                  \
        if (t < 15) {                                                               \
            int k0 = (t + 1) * 32;                                                  \
            _Pragma("unroll")                                                       \
            for (int i = 0; i < 2; i++) {                                           \
                int r0 = 32 * wid + 16 * i;                                         \
                async16(A_ + (size_t)(am0 + r0 + sr) * DIM_ + k0 + sc,              \
                        &Alds[buf ^ 1][r0][0]);                                     \
                async16(B_ptr + (size_t)(bn0 + r0 + sr) * DIM_ + k0 + sc,           \
                        &Blds[buf ^ 1][r0][0]);                                     \
            }                                                                       \
        }                                                                           \
        bf16x8 av[4], bv[4];                                                        \
        _Pragma("unroll")                                                           \
        for (int i = 0; i < 4; i++)                                                 \
            av[i] = *(const bf16x8*)(&Alds[buf][wmloc + 16 * i + l15][quad * 8]);   \
        _Pragma("unroll")                                                           \
        for (int j = 0; j < 4; j++)                                                 \
            bv[j] = *(const bf16x8*)(&Blds[buf][wnloc + 16 * j + l15][quad * 8]);   \
        _Pragma("unroll")                                                           \
        for (int i = 0; i < 4; i++)                                                 \
            _Pragma("unroll")                                                       \
            for (int j = 0; j < 4; j++)                                             \
                acc[i][j] = mfma16(av[i], bv[j], acc[i][j]);                        \
        __syncthreads();                                                            \
        buf ^= 1;                                                                   \
    }

// ---------------- QKV GEMM: [8192,512] x [1536,512]^T, scatter epilogue ----------------
__global__ __launch_bounds__(256, 4) void qkv_gemm(const unsigned short* __restrict__ A,
                                                   const unsigned short* __restrict__ Bw,
                                                   const float* __restrict__ bias,
                                                   unsigned short* __restrict__ Qh,
                                                   unsigned short* __restrict__ Kh,
                                                   unsigned short* __restrict__ Vt) {
    int am0 = blockIdx.x * 128, bn0 = blockIdx.y * 128;
    GEMM_CORE(A, Bw, am0, bn0)

#pragma unroll
    for (int i = 0; i < 4; i++) {
#pragma unroll
        for (int j = 0; j < 4; j++) {
            int n = bn0 + wnloc + 16 * j + l15;
            float bias_n = bias[n];
            int which = n >> 9;
            int rem = n & 511;
            int head = rem >> 6;
            int d = rem & 63;
#pragma unroll
            for (int r = 0; r < 4; r++) {
                int m = am0 + wmloc + 16 * i + quad * 4 + r;
                int b = m >> 11;
                int t = m & 2047;
                unsigned short h16 = f32_to_bf16(acc[i][j][r] + bias_n);
                if (which == 0)
                    Qh[((size_t)(b * NH_ + head) * N_ + t) * HD_ + d] = h16;
                else if (which == 1)
                    Kh[((size_t)(b * NH_ + head) * N_ + t) * HD_ + d] = h16;
                else
                    Vt[((size_t)(b * NH_ + head) * HD_ + d) * N_ + t] = h16;
            }
        }
    }
}

// ---------------- Out projection: [8192,512] x [512,512]^T + bias -> fp32 ----------------
__global__ __launch_bounds__(256, 4) void out_gemm(const unsigned short* __restrict__ A,
                                                   const unsigned short* __restrict__ Bw,
                                                   const float* __restrict__ bias,
                                                   float* __restrict__ out) {
    int am0 = blockIdx.x * 128, bn0 = blockIdx.y * 128;
    GEMM_CORE(A, Bw, am0, bn0)

#pragma unroll
    for (int i = 0; i < 4; i++) {
#pragma unroll
        for (int j = 0; j < 4; j++) {
            int n = bn0 + wnloc + 16 * j + l15;
            float bias_n = bias[n];
#pragma unroll
            for (int r = 0; r < 4; r++) {
                int m = am0 + wmloc + 16 * i + quad * 4 + r;
                out[(size_t)m * DIM_ + n] = acc[i][j][r] + bias_n;
            }
        }
    }
}

// ---------------- Flash attention, fixed-max softmax, LDS-staged K/V ----------------
// (unchanged from R5: 83 us, MfmaUtil 19.5%, 0 bank conflicts)
__global__ __launch_bounds__(256, 4) void attn_kernel(const unsigned short* __restrict__ Qh,
                                                      const unsigned short* __restrict__ Kh,
                                                      const unsigned short* __restrict__ Vtg,
                                                      unsigned short* __restrict__ Obuf) {
    int bh = blockIdx.y;
    int b = bh >> 3, head = bh & 7;
    int qt = blockIdx.x;
    int tid = threadIdx.x, lane = tid & 63, w = tid >> 6;
    int l15 = lane & 15, quad = lane >> 4;

    const unsigned short* Qp = Qh + (size_t)bh * N_ * HD_;
    const unsigned short* Kg = Kh + (size_t)bh * N_ * HD_;
    const unsigned short* Vg = Vtg + (size_t)bh * HD_ * N_;

    int q0 = qt * 64 + w * 16;

    bf16x8 aQ0 = *(const bf16x8*)(Qp + (size_t)(q0 + l15) * HD_ + quad * 8);
    bf16x8 aQ1 = *(const bf16x8*)(Qp + (size_t)(q0 + l15) * HD_ + 32 + quad * 8);

    floatx4 of[4];
#pragma unroll
    for (int t = 0; t < 4; t++) of[t] = fzero4();
    floatx4 lacc = fzero4();

    const short onebf = (short)0x3F80;   // bf16 1.0
    bf16x8 ones = {onebf, onebf, onebf, onebf, onebf, onebf, onebf, onebf};

    const float SL2E = SCALE_ * 1.44269504f;   // scale * log2(e)

    __shared__ unsigned short Kt[2][64][64];   // 16 KB
    __shared__ unsigned short Vs[2][64][64];   // 16 KB
    __shared__ unsigned short Pl[4][16][64];   //  8 KB

    int srow = lane >> 3;                 // 0..7
    int scol = ((lane & 7) ^ srow) * 8;   // shorts

#define STAGE(BUF, KV)                                                              \
    {                                                                               \
        _Pragma("unroll")                                                           \
        for (int i = 0; i < 2; i++) {                                               \
            int r0 = 16 * w + 8 * i;                                                \
            async16(Kg + (size_t)((KV) + r0 + srow) * HD_ + scol, &Kt[BUF][r0][0]); \
            async16(Vg + (size_t)(r0 + srow) * N_ + (KV) + scol, &Vs[BUF][r0][0]);  \
        }                                                                           \
    }

    STAGE(0, 0);
    __syncthreads();

    unsigned short* myP = &Pl[w][0][0];
    int buf = 0;
    for (int kv = 0; kv < N_; kv += 64) {
        if (kv + 64 < N_) STAGE(buf ^ 1, kv + 64);
        floatx4 c[4];
#pragma unroll
        for (int h = 0; h < 4; h++) {
            int krow = 16 * h + l15;
            int sw = l15 & 7;
            bf16x8 b0 = *(const bf16x8*)(&Kt[buf][krow][(quad ^ sw) * 8]);
            bf16x8 b1 = *(const bf16x8*)(&Kt[buf][krow][((quad + 4) ^ sw) * 8]);
            floatx4 cc = fzero4();
            cc = mfma16(aQ0, b0, cc);
            cc = mfma16(aQ1, b1, cc);
            c[h] = cc;
        }
#pragma unroll
        for (int h = 0; h < 4; h++)
#pragma unroll
            for (int r = 0; r < 4; r++) {
                int prow = quad * 4 + r;
                int unit = 2 * h + (l15 >> 3);
                myP[prow * 64 + ((unit ^ (prow & 7)) * 8) + (l15 & 7)] =
                    f32_to_bf16(exp2f(c[h][r] * SL2E));
            }
        {
            int sw = l15 & 7;
            bf16x8 aP0 = *(const bf16x8*)(myP + l15 * 64 + (quad ^ sw) * 8);
            bf16x8 aP1 = *(const bf16x8*)(myP + l15 * 64 + ((quad + 4) ^ sw) * 8);
#pragma unroll
            for (int t = 0; t < 4; t++) {
                int vrow = 16 * t + l15;
                bf16x8 v0 = *(const bf16x8*)(&Vs[buf][vrow][(quad ^ sw) * 8]);
                bf16x8 v1 = *(const bf16x8*)(&Vs[buf][vrow][((quad + 4) ^ sw) * 8]);
                of[t] = mfma16(aP0, v0, of[t]);
                of[t] = mfma16(aP1, v1, of[t]);
            }
            lacc = mfma16(aP0, ones, lacc);
            lacc = mfma16(aP1, ones, lacc);
        }
        __syncthreads();
        buf ^= 1;
    }
#undef STAGE

    float inv[4];
#pragma unroll
    for (int r = 0; r < 4; r++) inv[r] = 1.f / lacc[r];
#pragma unroll
    for (int t = 0; t < 4; t++) {
#pragma unroll
        for (int r = 0; r < 4; r++) {
            int t_tok = q0 + quad * 4 + r;
            int d = 16 * t + l15;
            Obuf[((size_t)b * N_ + t_tok) * DIM_ + head * HD_ + d] =
                f32_to_bf16(of[t][r] * inv[r]);
        }
    }
}

extern "C" void kernel_launch(void* const* d_in, const int* in_sizes, int n_in,
                              void* d_out, int out_size, void* d_ws, size_t ws_size,
                              hipStream_t stream) {
    const float* x     = (const float*)d_in[0];
    const float* ln_w  = (const float*)d_in[1];
    const float* ln_b  = (const float*)d_in[2];
    const float* qkv_w = (const float*)d_in[3];
    const float* qkv_b = (const float*)d_in[4];
    const float* out_w = (const float*)d_in[5];
    const float* out_b = (const float*)d_in[6];
    float* out = (float*)d_out;

    char* ws = (char*)d_ws;
    const size_t TOK = (size_t)B_ * N_;                 // 8192
    unsigned short* xn    = (unsigned short*)ws;  ws += TOK * DIM_ * 2;
    unsigned short* wq_bf = (unsigned short*)ws;  ws += (size_t)3 * DIM_ * DIM_ * 2;
    unsigned short* wo_bf = (unsigned short*)ws;  ws += (size_t)DIM_ * DIM_ * 2;
    unsigned short* Qh    = (unsigned short*)ws;  ws += TOK * DIM_ * 2;
    unsigned short* Kh    = (unsigned short*)ws;  ws += TOK * DIM_ * 2;
    unsigned short* Vt    = (unsigned short*)ws;  ws += TOK * DIM_ * 2;
    unsigned short* Obuf  = (unsigned short*)ws;  ws += TOK * DIM_ * 2;

    const int NW = 3 * DIM_ * DIM_;      // qkv_w elements
    const int NO = DIM_ * DIM_;          // out_w elements

    ln_kernel<<<TOK, 256, 0, stream>>>(x, ln_w, ln_b, xn);
    cvt_kernel<<<(NW + NO + 255) / 256, 256, 0, stream>>>(qkv_w, NW, out_w, NO, wq_bf, wo_bf);
    qkv_gemm<<<dim3(TOK / 128, (3 * DIM_) / 128), 256, 0, stream>>>(xn, wq_bf, qkv_b, Qh, Kh, Vt);
    attn_kernel<<<dim3(N_ / 64, B_ * NH_), 256, 0, stream>>>(Qh, Kh, Vt, Obuf);
    out_gemm<<<dim3(TOK / 128, DIM_ / 128), 256, 0, stream>>>(Obuf, wo_bf, out_b, out);
}

// Round 7
// 190.800 us; speedup vs baseline: 2.0697x; 1.0135x over previous
//
#include <hip/hip_runtime.h>

typedef __attribute__((ext_vector_type(8))) short bf16x8;
typedef __attribute__((ext_vector_type(4))) float floatx4;

#define B_    4
#define N_    2048
#define DIM_  512
#define NH_   8
#define HD_   64
#define SCALE_ 0.125f
#define SL2E_ (0.125f * 1.44269504f)   // scale * log2(e), folded into Q

__device__ __forceinline__ unsigned short f32_to_bf16(float f) {
    unsigned int u = __float_as_uint(f);
    u += 0x7FFFu + ((u >> 16) & 1u);   // round-to-nearest-even
    return (unsigned short)(u >> 16);
}

__device__ __forceinline__ floatx4 mfma16(bf16x8 a, bf16x8 b, floatx4 c) {
    return __builtin_amdgcn_mfma_f32_16x16x32_bf16(a, b, c, 0, 0, 0);
}

__device__ __forceinline__ floatx4 fzero4() {
    floatx4 z = {0.f, 0.f, 0.f, 0.f};
    return z;
}

// async global->LDS DMA, 16B per lane. lds dest is wave-uniform base; HW adds lane*16.
__device__ __forceinline__ void async16(const unsigned short* g, unsigned short* l) {
    __builtin_amdgcn_global_load_lds((const __attribute__((address_space(1))) void*)g,
                                     (__attribute__((address_space(3))) void*)l,
                                     16, 0, 0);
}

// ---------------- LayerNorm: x[8192][512] fp32 -> xn bf16 ----------------
__global__ __launch_bounds__(256) void ln_kernel(const float* __restrict__ x,
                                                 const float* __restrict__ w,
                                                 const float* __restrict__ b,
                                                 unsigned short* __restrict__ xn) {
    int row = blockIdx.x;
    int tid = threadIdx.x;
    int lane = tid & 63, wid = tid >> 6;
    const float2 v = ((const float2*)(x + (size_t)row * DIM_))[tid];
    float s = v.x + v.y;
    float sq = v.x * v.x + v.y * v.y;
#pragma unroll
    for (int off = 1; off < 64; off <<= 1) {
        s  += __shfl_xor(s, off, 64);
        sq += __shfl_xor(sq, off, 64);
    }
    __shared__ float red[2][4];
    if (lane == 0) { red[0][wid] = s; red[1][wid] = sq; }
    __syncthreads();
    s  = red[0][0] + red[0][1] + red[0][2] + red[0][3];
    sq = red[1][0] + red[1][1] + red[1][2] + red[1][3];
    float mu   = s * (1.f / DIM_);
    float var  = sq * (1.f / DIM_) - mu * mu;
    float rstd = rsqrtf(var + 1e-5f);
    float2 wv = ((const float2*)w)[tid];
    float2 bv = ((const float2*)b)[tid];
    float y0 = (v.x - mu) * rstd * wv.x + bv.x;
    float y1 = (v.y - mu) * rstd * wv.y + bv.y;
    unsigned int pack = (unsigned int)f32_to_bf16(y0) |
                        ((unsigned int)f32_to_bf16(y1) << 16);
    ((unsigned int*)xn)[(size_t)row * (DIM_ / 2) + tid] = pack;
}

// ---------------- fp32 -> bf16 convert (both weight matrices, one launch) ----------------
__global__ __launch_bounds__(256) void cvt_kernel(const float* __restrict__ srcA, int na,
                                                  const float* __restrict__ srcB, int nb,
                                                  unsigned short* __restrict__ dstA,
                                                  unsigned short* __restrict__ dstB) {
    int idx = blockIdx.x * 256 + threadIdx.x;
    if (idx < na)            dstA[idx] = f32_to_bf16(srcA[idx]);
    else if (idx < na + nb)  dstB[idx - na] = f32_to_bf16(srcB[idx - na]);
}

// ================= m97-style LDS-staged GEMM core (shared by both GEMMs) =================
#define GEMM_CORE(A_, B_ptr, am0, bn0)                                              \
    __shared__ unsigned short Alds[2][128][32];                                     \
    __shared__ unsigned short Blds[2][128][32];                                     \
    int tid = threadIdx.x, lane = tid & 63, wid = tid >> 6;                         \
    int l15 = lane & 15, quad = lane >> 4;                                          \
    int wmloc = (wid >> 1) * 64, wnloc = (wid & 1) * 64;                            \
    int sr = lane >> 2;                                                             \
    int sc = (lane & 3) * 8;                                                        \
    floatx4 acc[4][4];                                                              \
    _Pragma("unroll")                                                               \
    for (int i = 0; i < 4; i++)                                                     \
        _Pragma("unroll")                                                           \
        for (int j = 0; j < 4; j++) acc[i][j] = fzero4();                           \
    int buf = 0;                                                                    \
    _Pragma("unroll")                                                               \
    for (int i = 0; i < 2; i++) {                                                   \
        int r0 = 32 * wid + 16 * i;                                                 \
        async16(A_ + (size_t)(am0 + r0 + sr) * DIM_ + sc, &Alds[0][r0][0]);         \
        async16(B_ptr + (size_t)(bn0 + r0 + sr) * DIM_ + sc, &Blds[0][r0][0]);      \
    }                                                                               \
    __syncthreads();                                                                \
    for (int t = 0; t < 16; t++) {                                                  \
        if (t < 15) {                                                               \
            int k0 = (t + 1) * 32;                                                  \
            _Pragma("unroll")                                                       \
            for (int i = 0; i < 2; i++) {                                           \
                int r0 = 32 * wid + 16 * i;                                         \
                async16(A_ + (size_t)(am0 + r0 + sr) * DIM_ + k0 + sc,              \
                        &Alds[buf ^ 1][r0][0]);                                     \
                async16(B_ptr + (size_t)(bn0 + r0 + sr) * DIM_ + k0 + sc,           \
                        &Blds[buf ^ 1][r0][0]);                                     \
            }                                                                       \
        }                                                                           \
        bf16x8 av[4], bv[4];                                                        \
        _Pragma("unroll")                                                           \
        for (int i = 0; i < 4; i++)                                                 \
            av[i] = *(const bf16x8*)(&Alds[buf][wmloc + 16 * i + l15][quad * 8]);   \
        _Pragma("unroll")                                                           \
        for (int j = 0; j < 4; j++)                                                 \
            bv[j] = *(const bf16x8*)(&Blds[buf][wnloc + 16 * j + l15][quad * 8]);   \
        _Pragma("unroll")                                                           \
        for (int i = 0; i < 4; i++)                                                 \
            _Pragma("unroll")                                                       \
            for (int j = 0; j < 4; j++)                                             \
                acc[i][j] = mfma16(av[i], bv[j], acc[i][j]);                        \
        __syncthreads();                                                            \
        buf ^= 1;                                                                   \
    }

// ---------------- QKV GEMM: [8192,512] x [1536,512]^T, scatter epilogue ----------------
// Q outputs pre-scaled by SL2E_ so attention can exp2() scores directly.
__global__ __launch_bounds__(256, 4) void qkv_gemm(const unsigned short* __restrict__ A,
                                                   const unsigned short* __restrict__ Bw,
                                                   const float* __restrict__ bias,
                                                   unsigned short* __restrict__ Qh,
                                                   unsigned short* __restrict__ Kh,
                                                   unsigned short* __restrict__ Vt) {
    int am0 = blockIdx.x * 128, bn0 = blockIdx.y * 128;
    GEMM_CORE(A, Bw, am0, bn0)

#pragma unroll
    for (int i = 0; i < 4; i++) {
#pragma unroll
        for (int j = 0; j < 4; j++) {
            int n = bn0 + wnloc + 16 * j + l15;
            float bias_n = bias[n];
            int which = n >> 9;
            int rem = n & 511;
            int head = rem >> 6;
            int d = rem & 63;
#pragma unroll
            for (int r = 0; r < 4; r++) {
                int m = am0 + wmloc + 16 * i + quad * 4 + r;
                int b = m >> 11;
                int t = m & 2047;
                float val = acc[i][j][r] + bias_n;
                if (which == 0) {
                    Qh[((size_t)(b * NH_ + head) * N_ + t) * HD_ + d] =
                        f32_to_bf16(val * SL2E_);
                } else if (which == 1) {
                    Kh[((size_t)(b * NH_ + head) * N_ + t) * HD_ + d] = f32_to_bf16(val);
                } else {
                    Vt[((size_t)(b * NH_ + head) * HD_ + d) * N_ + t] = f32_to_bf16(val);
                }
            }
        }
    }
}

// ---------------- Out projection: [8192,512] x [512,512]^T + bias -> fp32 ----------------
__global__ __launch_bounds__(256, 4) void out_gemm(const unsigned short* __restrict__ A,
                                                   const unsigned short* __restrict__ Bw,
                                                   const float* __restrict__ bias,
                                                   float* __restrict__ out) {
    int am0 = blockIdx.x * 128, bn0 = blockIdx.y * 128;
    GEMM_CORE(A, Bw, am0, bn0)

#pragma unroll
    for (int i = 0; i < 4; i++) {
#pragma unroll
        for (int j = 0; j < 4; j++) {
            int n = bn0 + wnloc + 16 * j + l15;
            float bias_n = bias[n];
#pragma unroll
            for (int r = 0; r < 4; r++) {
                int m = am0 + wmloc + 16 * i + quad * 4 + r;
                out[(size_t)m * DIM_ + n] = acc[i][j][r] + bias_n;
            }
        }
    }
}

// ---------------- Flash attention, fixed-max softmax, LDS-staged K/V ----------------
// 32 q-rows per wave (two 16-row m-halves sharing K/V fragment reads -> ~1.8x
// less LDS read traffic per FLOP). Block = 4 waves = 128 q-rows; grid (16,32)
// = 512 blocks = 2/CU. P tile padded stride-72 (wave-private; immediate-offset
// DS ops, no per-element XOR). Q arrives pre-scaled by scale*log2e.
__global__ __launch_bounds__(256, 2) void attn_kernel(const unsigned short* __restrict__ Qh,
                                                      const unsigned short* __restrict__ Kh,
                                                      const unsigned short* __restrict__ Vtg,
                                                      unsigned short* __restrict__ Obuf) {
    int bh = blockIdx.y;
    int b = bh >> 3, head = bh & 7;
    int qt = blockIdx.x;
    int tid = threadIdx.x, lane = tid & 63, w = tid >> 6;
    int l15 = lane & 15, quad = lane >> 4;

    const unsigned short* Qp = Qh + (size_t)bh * N_ * HD_;
    const unsigned short* Kg = Kh + (size_t)bh * N_ * HD_;
    const unsigned short* Vg = Vtg + (size_t)bh * HD_ * N_;

    int q0 = qt * 128 + w * 32;

    bf16x8 aQ[2][2];
#pragma unroll
    for (int mh = 0; mh < 2; mh++) {
        const unsigned short* qrow = Qp + (size_t)(q0 + mh * 16 + l15) * HD_ + quad * 8;
        aQ[mh][0] = *(const bf16x8*)(qrow);
        aQ[mh][1] = *(const bf16x8*)(qrow + 32);
    }

    floatx4 of[2][4];
#pragma unroll
    for (int mh = 0; mh < 2; mh++)
#pragma unroll
        for (int t = 0; t < 4; t++) of[mh][t] = fzero4();
    floatx4 lacc[2];
    lacc[0] = fzero4(); lacc[1] = fzero4();

    const short onebf = (short)0x3F80;   // bf16 1.0
    bf16x8 ones = {onebf, onebf, onebf, onebf, onebf, onebf, onebf, onebf};

    __shared__ unsigned short Kt[2][64][64];   // 16 KB, XOR-swizzled (DMA constraint)
    __shared__ unsigned short Vs[2][64][64];   // 16 KB, XOR-swizzled
    __shared__ unsigned short Pl[4][32][72];   // 18 KB, wave-private, padded

    int srow = lane >> 3;                 // 0..7
    int scol = ((lane & 7) ^ srow) * 8;   // shorts

    // lane-constant fragment offsets into the swizzled K/V tiles
    int swz0 = (quad ^ (l15 & 7)) * 8;
    int swz1 = ((quad + 4) ^ (l15 & 7)) * 8;

#define STAGE(BUF, KV)                                                              \
    {                                                                               \
        _Pragma("unroll")                                                           \
        for (int i = 0; i < 2; i++) {                                               \
            int r0 = 16 * w + 8 * i;                                                \
            async16(Kg + (size_t)((KV) + r0 + srow) * HD_ + scol, &Kt[BUF][r0][0]); \
            async16(Vg + (size_t)(r0 + srow) * N_ + (KV) + scol, &Vs[BUF][r0][0]);  \
        }                                                                           \
    }

    STAGE(0, 0);
    __syncthreads();

    unsigned short* myP = &Pl[w][0][0];
    int buf = 0;
    for (int kv = 0; kv < N_; kv += 64) {
        if (kv + 64 < N_) STAGE(buf ^ 1, kv + 64);
        // ---- K fragments (shared by both m-halves) ----
        bf16x8 kf[8];
#pragma unroll
        for (int h = 0; h < 4; h++) {
            kf[2 * h]     = *(const bf16x8*)(&Kt[buf][16 * h + l15][swz0]);
            kf[2 * h + 1] = *(const bf16x8*)(&Kt[buf][16 * h + l15][swz1]);
        }
        // ---- S = Q K^T, P = exp2(S) -> LDS, per m-half ----
#pragma unroll
        for (int mh = 0; mh < 2; mh++) {
            floatx4 c[4];
#pragma unroll
            for (int h = 0; h < 4; h++) {
                floatx4 cc = fzero4();
                cc = mfma16(aQ[mh][0], kf[2 * h], cc);
                cc = mfma16(aQ[mh][1], kf[2 * h + 1], cc);
                c[h] = cc;
            }
            unsigned short* pw = myP + (mh * 16 + quad * 4) * 72 + l15;
#pragma unroll
            for (int h = 0; h < 4; h++)
#pragma unroll
                for (int r = 0; r < 4; r++)
                    pw[r * 72 + h * 16] = f32_to_bf16(exp2f(c[h][r]));
        }
        // ---- V fragments (shared by both m-halves) ----
        bf16x8 vf[8];
#pragma unroll
        for (int t = 0; t < 4; t++) {
            vf[2 * t]     = *(const bf16x8*)(&Vs[buf][16 * t + l15][swz0]);
            vf[2 * t + 1] = *(const bf16x8*)(&Vs[buf][16 * t + l15][swz1]);
        }
        // ---- O += P V ; l += P * ones ----
#pragma unroll
        for (int mh = 0; mh < 2; mh++) {
            const unsigned short* pr = myP + (mh * 16 + l15) * 72;
            bf16x8 aP0 = *(const bf16x8*)(pr + quad * 8);
            bf16x8 aP1 = *(const bf16x8*)(pr + 32 + quad * 8);
#pragma unroll
            for (int t = 0; t < 4; t++) {
                of[mh][t] = mfma16(aP0, vf[2 * t], of[mh][t]);
                of[mh][t] = mfma16(aP1, vf[2 * t + 1], of[mh][t]);
            }
            lacc[mh] = mfma16(aP0, ones, lacc[mh]);
            lacc[mh] = mfma16(aP1, ones, lacc[mh]);
        }
        __syncthreads();
        buf ^= 1;
    }
#undef STAGE

#pragma unroll
    for (int mh = 0; mh < 2; mh++) {
        float inv[4];
#pragma unroll
        for (int r = 0; r < 4; r++) inv[r] = 1.f / lacc[mh][r];
#pragma unroll
        for (int t = 0; t < 4; t++) {
#pragma unroll
            for (int r = 0; r < 4; r++) {
                int t_tok = q0 + mh * 16 + quad * 4 + r;
                int d = 16 * t + l15;
                Obuf[((size_t)b * N_ + t_tok) * DIM_ + head * HD_ + d] =
                    f32_to_bf16(of[mh][t][r] * inv[r]);
            }
        }
    }
}

extern "C" void kernel_launch(void* const* d_in, const int* in_sizes, int n_in,
                              void* d_out, int out_size, void* d_ws, size_t ws_size,
                              hipStream_t stream) {
    const float* x     = (const float*)d_in[0];
    const float* ln_w  = (const float*)d_in[1];
    const float* ln_b  = (const float*)d_in[2];
    const float* qkv_w = (const float*)d_in[3];
    const float* qkv_b = (const float*)d_in[4];
    const float* out_w = (const float*)d_in[5];
    const float* out_b = (const float*)d_in[6];
    float* out = (float*)d_out;

    char* ws = (char*)d_ws;
    const size_t TOK = (size_t)B_ * N_;                 // 8192
    unsigned short* xn    = (unsigned short*)ws;  ws += TOK * DIM_ * 2;
    unsigned short* wq_bf = (unsigned short*)ws;  ws += (size_t)3 * DIM_ * DIM_ * 2;
    unsigned short* wo_bf = (unsigned short*)ws;  ws += (size_t)DIM_ * DIM_ * 2;
    unsigned short* Qh    = (unsigned short*)ws;  ws += TOK * DIM_ * 2;
    unsigned short* Kh    = (unsigned short*)ws;  ws += TOK * DIM_ * 2;
    unsigned short* Vt    = (unsigned short*)ws;  ws += TOK * DIM_ * 2;
    unsigned short* Obuf  = (unsigned short*)ws;  ws += TOK * DIM_ * 2;

    const int NW = 3 * DIM_ * DIM_;      // qkv_w elements
    const int NO = DIM_ * DIM_;          // out_w elements

    ln_kernel<<<TOK, 256, 0, stream>>>(x, ln_w, ln_b, xn);
    cvt_kernel<<<(NW + NO + 255) / 256, 256, 0, stream>>>(qkv_w, NW, out_w, NO, wq_bf, wo_bf);
    qkv_gemm<<<dim3(TOK / 128, (3 * DIM_) / 128), 256, 0, stream>>>(xn, wq_bf, qkv_b, Qh, Kh, Vt);
    attn_kernel<<<dim3(N_ / 128, B_ * NH_), 256, 0, stream>>>(Qh, Kh, Vt, Obuf);
    out_gemm<<<dim3(TOK / 128, DIM_ / 128), 256, 0, stream>>>(Obuf, wo_bf, out_b, out);
}

// Round 8
// 190.397 us; speedup vs baseline: 2.0741x; 1.0021x over previous
//
#include <hip/hip_runtime.h>

typedef __attribute__((ext_vector_type(8))) short bf16x8;
typedef __attribute__((ext_vector_type(4))) float floatx4;

#define B_    4
#define N_    2048
#define DIM_  512
#define NH_   8
#define HD_   64
#define SCALE_ 0.125f
#define SL2E_ (0.125f * 1.44269504f)   // scale * log2(e), folded into Q

__device__ __forceinline__ unsigned short f32_to_bf16(float f) {
    unsigned int u = __float_as_uint(f);
    u += 0x7FFFu + ((u >> 16) & 1u);   // round-to-nearest-even
    return (unsigned short)(u >> 16);
}

__device__ __forceinline__ float bf16_to_f32(unsigned short u) {
    return __uint_as_float(((unsigned int)u) << 16);
}

__device__ __forceinline__ floatx4 mfma16(bf16x8 a, bf16x8 b, floatx4 c) {
    return __builtin_amdgcn_mfma_f32_16x16x32_bf16(a, b, c, 0, 0, 0);
}

__device__ __forceinline__ floatx4 fzero4() {
    floatx4 z = {0.f, 0.f, 0.f, 0.f};
    return z;
}

// async global->LDS DMA, 16B per lane. lds dest is wave-uniform base; HW adds lane*16.
__device__ __forceinline__ void async16(const unsigned short* g, unsigned short* l) {
    __builtin_amdgcn_global_load_lds((const __attribute__((address_space(1))) void*)g,
                                     (__attribute__((address_space(3))) void*)l,
                                     16, 0, 0);
}

// ---------------- LayerNorm: x[8192][512] fp32 -> xn bf16 ----------------
__global__ __launch_bounds__(256) void ln_kernel(const float* __restrict__ x,
                                                 const float* __restrict__ w,
                                                 const float* __restrict__ b,
                                                 unsigned short* __restrict__ xn) {
    int row = blockIdx.x;
    int tid = threadIdx.x;
    int lane = tid & 63, wid = tid >> 6;
    const float2 v = ((const float2*)(x + (size_t)row * DIM_))[tid];
    float s = v.x + v.y;
    float sq = v.x * v.x + v.y * v.y;
#pragma unroll
    for (int off = 1; off < 64; off <<= 1) {
        s  += __shfl_xor(s, off, 64);
        sq += __shfl_xor(sq, off, 64);
    }
    __shared__ float red[2][4];
    if (lane == 0) { red[0][wid] = s; red[1][wid] = sq; }
    __syncthreads();
    s  = red[0][0] + red[0][1] + red[0][2] + red[0][3];
    sq = red[1][0] + red[1][1] + red[1][2] + red[1][3];
    float mu   = s * (1.f / DIM_);
    float var  = sq * (1.f / DIM_) - mu * mu;
    float rstd = rsqrtf(var + 1e-5f);
    float2 wv = ((const float2*)w)[tid];
    float2 bv = ((const float2*)b)[tid];
    float y0 = (v.x - mu) * rstd * wv.x + bv.x;
    float y1 = (v.y - mu) * rstd * wv.y + bv.y;
    unsigned int pack = (unsigned int)f32_to_bf16(y0) |
                        ((unsigned int)f32_to_bf16(y1) << 16);
    ((unsigned int*)xn)[(size_t)row * (DIM_ / 2) + tid] = pack;
}

// ---------------- fp32 -> bf16 convert (both weight matrices, one launch) ----------------
__global__ __launch_bounds__(256) void cvt_kernel(const float* __restrict__ srcA, int na,
                                                  const float* __restrict__ srcB, int nb,
                                                  unsigned short* __restrict__ dstA,
                                                  unsigned short* __restrict__ dstB) {
    int idx = blockIdx.x * 256 + threadIdx.x;
    if (idx < na)            dstA[idx] = f32_to_bf16(srcA[idx]);
    else if (idx < na + nb)  dstB[idx - na] = f32_to_bf16(srcB[idx - na]);
}

// ================= m97-style LDS-staged GEMM core (shared by both GEMMs) =================
#define GEMM_CORE(A_, B_ptr, am0, bn0)                                              \
    __shared__ unsigned short Alds[2][128][32];                                     \
    __shared__ unsigned short Blds[2][128][32];                                     \
    int tid = threadIdx.x, lane = tid & 63, wid = tid >> 6;                         \
    int l15 = lane & 15, quad = lane >> 4;                                          \
    int wmloc = (wid >> 1) * 64, wnloc = (wid & 1) * 64;                            \
    int sr = lane >> 2;                                                             \
    int sc = (lane & 3) * 8;                                                        \
    floatx4 acc[4][4];                                                              \
    _Pragma("unroll")                                                               \
    for (int i = 0; i < 4; i++)                                                     \
        _Pragma("unroll")                                                           \
        for (int j = 0; j < 4; j++) acc[i][j] = fzero4();                           \
    int buf = 0;                                                                    \
    _Pragma("unroll")                                                               \
    for (int i = 0; i < 2; i++) {                                                   \
        int r0 = 32 * wid + 16 * i;                                                 \
        async16(A_ + (size_t)(am0 + r0 + sr) * DIM_ + sc, &Alds[0][r0][0]);         \
        async16(B_ptr + (size_t)(bn0 + r0 + sr) * DIM_ + sc, &Blds[0][r0][0]);      \
    }                                                                               \
    __syncthreads();                                                                \
    for (int t = 0; t < 16; t++) {                                                  \
        if (t < 15) {                                                               \
            int k0 = (t + 1) * 32;                                                  \
            _Pragma("unroll")                                                       \
            for (int i = 0; i < 2; i++) {                                           \
                int r0 = 32 * wid + 16 * i;                                         \
                async16(A_ + (size_t)(am0 + r0 + sr) * DIM_ + k0 + sc,              \
                        &Alds[buf ^ 1][r0][0]);                                     \
                async16(B_ptr + (size_t)(bn0 + r0 + sr) * DIM_ + k0 + sc,           \
                        &Blds[buf ^ 1][r0][0]);                                     \
            }                                                                       \
        }                                                                           \
        bf16x8 av[4], bv[4];                                                        \
        _Pragma("unroll")                                                           \
        for (int i = 0; i < 4; i++)                                                 \
            av[i] = *(const bf16x8*)(&Alds[buf][wmloc + 16 * i + l15][quad * 8]);   \
        _Pragma("unroll")                                                           \
        for (int j = 0; j < 4; j++)                                                 \
            bv[j] = *(const bf16x8*)(&Blds[buf][wnloc + 16 * j + l15][quad * 8]);   \
        _Pragma("unroll")                                                           \
        for (int i = 0; i < 4; i++)                                                 \
            _Pragma("unroll")                                                       \
            for (int j = 0; j < 4; j++)                                             \
                acc[i][j] = mfma16(av[i], bv[j], acc[i][j]);                        \
        __syncthreads();                                                            \
        buf ^= 1;                                                                   \
    }

// ---------------- QKV GEMM: [8192,512] x [1536,512]^T, scatter epilogue ----------------
__global__ __launch_bounds__(256, 4) void qkv_gemm(const unsigned short* __restrict__ A,
                                                   const unsigned short* __restrict__ Bw,
                                                   const float* __restrict__ bias,
                                                   unsigned short* __restrict__ Qh,
                                                   unsigned short* __restrict__ Kh,
                                                   unsigned short* __restrict__ Vt) {
    int am0 = blockIdx.x * 128, bn0 = blockIdx.y * 128;
    GEMM_CORE(A, Bw, am0, bn0)

#pragma unroll
    for (int i = 0; i < 4; i++) {
#pragma unroll
        for (int j = 0; j < 4; j++) {
            int n = bn0 + wnloc + 16 * j + l15;
            float bias_n = bias[n];
            int which = n >> 9;
            int rem = n & 511;
            int head = rem >> 6;
            int d = rem & 63;
#pragma unroll
            for (int r = 0; r < 4; r++) {
                int m = am0 + wmloc + 16 * i + quad * 4 + r;
                int b = m >> 11;
                int t = m & 2047;
                float val = acc[i][j][r] + bias_n;
                if (which == 0) {
                    Qh[((size_t)(b * NH_ + head) * N_ + t) * HD_ + d] =
                        f32_to_bf16(val * SL2E_);
                } else if (which == 1) {
                    Kh[((size_t)(b * NH_ + head) * N_ + t) * HD_ + d] = f32_to_bf16(val);
                } else {
                    Vt[((size_t)(b * NH_ + head) * HD_ + d) * N_ + t] = f32_to_bf16(val);
                }
            }
        }
    }
}

// ---------------- Out projection: [8192,512] x [512,512]^T + bias -> fp32 ----------------
__global__ __launch_bounds__(256, 4) void out_gemm(const unsigned short* __restrict__ A,
                                                   const unsigned short* __restrict__ Bw,
                                                   const float* __restrict__ bias,
                                                   float* __restrict__ out) {
    int am0 = blockIdx.x * 128, bn0 = blockIdx.y * 128;
    GEMM_CORE(A, Bw, am0, bn0)

#pragma unroll
    for (int i = 0; i < 4; i++) {
#pragma unroll
        for (int j = 0; j < 4; j++) {
            int n = bn0 + wnloc + 16 * j + l15;
            float bias_n = bias[n];
#pragma unroll
            for (int r = 0; r < 4; r++) {
                int m = am0 + wmloc + 16 * i + quad * 4 + r;
                out[(size_t)m * DIM_ + n] = acc[i][j][r] + bias_n;
            }
        }
    }
}

// ---------------- Flash attention, fixed-max softmax, split-KV x2 ----------------
// grid (16 qtiles, 32 bh, 2 splits) = 1024 blocks -> 4 blocks/CU (LDS 34 KB,
// single-buffered K/V: stage -> barrier -> compute -> barrier; inter-block
// overlap at 4 blocks/CU hides the DMA wait). Each block covers 128 q-rows
// (4 waves x 32) and 1024 kv, writing self-normalized partial O (bf16) and
// partial row-sum l (fp32). combine_kernel merges the two splits exactly:
// O = (l1*Obar1 + l2*Obar2)/(l1+l2).
__global__ __launch_bounds__(256, 4) void attn_kernel(const unsigned short* __restrict__ Qh,
                                                      const unsigned short* __restrict__ Kh,
                                                      const unsigned short* __restrict__ Vtg,
                                                      unsigned short* __restrict__ Opart,
                                                      float* __restrict__ lpart) {
    int bh = blockIdx.y;
    int b = bh >> 3, head = bh & 7;
    int qt = blockIdx.x;
    int split = blockIdx.z;
    int kv0 = split << 10;                 // 0 or 1024
    int tid = threadIdx.x, lane = tid & 63, w = tid >> 6;
    int l15 = lane & 15, quad = lane >> 4;

    const unsigned short* Qp = Qh + (size_t)bh * N_ * HD_;
    const unsigned short* Kg = Kh + (size_t)bh * N_ * HD_;
    const unsigned short* Vg = Vtg + (size_t)bh * HD_ * N_;

    int q0 = qt * 128 + w * 32;

    bf16x8 aQ[2][2];
#pragma unroll
    for (int mh = 0; mh < 2; mh++) {
        const unsigned short* qrow = Qp + (size_t)(q0 + mh * 16 + l15) * HD_ + quad * 8;
        aQ[mh][0] = *(const bf16x8*)(qrow);
        aQ[mh][1] = *(const bf16x8*)(qrow + 32);
    }

    floatx4 of[2][4];
#pragma unroll
    for (int mh = 0; mh < 2; mh++)
#pragma unroll
        for (int t = 0; t < 4; t++) of[mh][t] = fzero4();
    floatx4 lacc[2];
    lacc[0] = fzero4(); lacc[1] = fzero4();

    const short onebf = (short)0x3F80;   // bf16 1.0
    bf16x8 ones = {onebf, onebf, onebf, onebf, onebf, onebf, onebf, onebf};

    __shared__ unsigned short Kt[64][64];      // 8 KB, XOR-swizzled, single-buffered
    __shared__ unsigned short Vs[64][64];      // 8 KB
    __shared__ unsigned short Pl[4][32][72];   // 18 KB, wave-private, padded

    int srow = lane >> 3;                 // 0..7
    int scol = ((lane & 7) ^ srow) * 8;   // shorts

    int swz0 = (quad ^ (l15 & 7)) * 8;
    int swz1 = ((quad + 4) ^ (l15 & 7)) * 8;

    unsigned short* myP = &Pl[w][0][0];
    for (int kv = kv0; kv < kv0 + 1024; kv += 64) {
        // ---- stage K/V tile (4 async16 per wave), then wait ----
#pragma unroll
        for (int i = 0; i < 2; i++) {
            int r0 = 16 * w + 8 * i;
            async16(Kg + (size_t)(kv + r0 + srow) * HD_ + scol, &Kt[r0][0]);
            async16(Vg + (size_t)(r0 + srow) * N_ + kv + scol, &Vs[r0][0]);
        }
        __syncthreads();
        // ---- K fragments (shared by both m-halves) ----
        bf16x8 kf[8];
#pragma unroll
        for (int h = 0; h < 4; h++) {
            kf[2 * h]     = *(const bf16x8*)(&Kt[16 * h + l15][swz0]);
            kf[2 * h + 1] = *(const bf16x8*)(&Kt[16 * h + l15][swz1]);
        }
        // ---- S = Q K^T, P = exp2(S) -> LDS ----
#pragma unroll
        for (int mh = 0; mh < 2; mh++) {
            floatx4 c[4];
#pragma unroll
            for (int h = 0; h < 4; h++) {
                floatx4 cc = fzero4();
                cc = mfma16(aQ[mh][0], kf[2 * h], cc);
                cc = mfma16(aQ[mh][1], kf[2 * h + 1], cc);
                c[h] = cc;
            }
            unsigned short* pw = myP + (mh * 16 + quad * 4) * 72 + l15;
#pragma unroll
            for (int h = 0; h < 4; h++)
#pragma unroll
                for (int r = 0; r < 4; r++)
                    pw[r * 72 + h * 16] = f32_to_bf16(exp2f(c[h][r]));
        }
        // ---- V fragments (shared by both m-halves) ----
        bf16x8 vf[8];
#pragma unroll
        for (int t = 0; t < 4; t++) {
            vf[2 * t]     = *(const bf16x8*)(&Vs[16 * t + l15][swz0]);
            vf[2 * t + 1] = *(const bf16x8*)(&Vs[16 * t + l15][swz1]);
        }
        // ---- O += P V ; l += P * ones ----
#pragma unroll
        for (int mh = 0; mh < 2; mh++) {
            const unsigned short* pr = myP + (mh * 16 + l15) * 72;
            bf16x8 aP0 = *(const bf16x8*)(pr + quad * 8);
            bf16x8 aP1 = *(const bf16x8*)(pr + 32 + quad * 8);
#pragma unroll
            for (int t = 0; t < 4; t++) {
                of[mh][t] = mfma16(aP0, vf[2 * t], of[mh][t]);
                of[mh][t] = mfma16(aP1, vf[2 * t + 1], of[mh][t]);
            }
            lacc[mh] = mfma16(aP0, ones, lacc[mh]);
            lacc[mh] = mfma16(aP1, ones, lacc[mh]);
        }
        __syncthreads();   // all waves done reading before next stage overwrites
    }

    unsigned short* Od = Opart + (size_t)split * B_ * N_ * DIM_;
#pragma unroll
    for (int mh = 0; mh < 2; mh++) {
        float inv[4];
#pragma unroll
        for (int r = 0; r < 4; r++) inv[r] = 1.f / lacc[mh][r];
#pragma unroll
        for (int t = 0; t < 4; t++) {
#pragma unroll
            for (int r = 0; r < 4; r++) {
                int t_tok = q0 + mh * 16 + quad * 4 + r;
                int d = 16 * t + l15;
                Od[((size_t)b * N_ + t_tok) * DIM_ + head * HD_ + d] =
                    f32_to_bf16(of[mh][t][r] * inv[r]);
            }
        }
        if (l15 == 0) {
#pragma unroll
            for (int r = 0; r < 4; r++) {
                int t_tok = q0 + mh * 16 + quad * 4 + r;
                lpart[(size_t)split * B_ * NH_ * N_ + (size_t)bh * N_ + t_tok] =
                    lacc[mh][r];
            }
        }
    }
}

// ---------------- combine: Obuf = (l1*O1 + l2*O2)/(l1+l2), bf16 ----------------
__global__ __launch_bounds__(256) void combine_kernel(const unsigned short* __restrict__ Opart,
                                                      const float* __restrict__ lpart,
                                                      unsigned short* __restrict__ Obuf) {
    int idx = blockIdx.x * 256 + threadIdx.x;   // 4-element groups, 1048576 total
    int row = idx >> 7;                         // token row 0..8191
    int head = (idx & 127) >> 4;                // (4*colg)>>6
    int b = row >> 11, t = row & 2047;
    size_t li = (size_t)(b * NH_ + head) * N_ + t;
    float l1 = lpart[li];
    float l2 = lpart[(size_t)B_ * NH_ * N_ + li];
    float s = 1.f / (l1 + l2);
    float w1 = l1 * s, w2 = l2 * s;
    const size_t half = (size_t)B_ * N_ * DIM_;
    ushort4 a = ((const ushort4*)Opart)[idx];
    ushort4 c = ((const ushort4*)(Opart + half))[idx];
    ushort4 o;
    o.x = f32_to_bf16(w1 * bf16_to_f32(a.x) + w2 * bf16_to_f32(c.x));
    o.y = f32_to_bf16(w1 * bf16_to_f32(a.y) + w2 * bf16_to_f32(c.y));
    o.z = f32_to_bf16(w1 * bf16_to_f32(a.z) + w2 * bf16_to_f32(c.z));
    o.w = f32_to_bf16(w1 * bf16_to_f32(a.w) + w2 * bf16_to_f32(c.w));
    ((ushort4*)Obuf)[idx] = o;
}

extern "C" void kernel_launch(void* const* d_in, const int* in_sizes, int n_in,
                              void* d_out, int out_size, void* d_ws, size_t ws_size,
                              hipStream_t stream) {
    const float* x     = (const float*)d_in[0];
    const float* ln_w  = (const float*)d_in[1];
    const float* ln_b  = (const float*)d_in[2];
    const float* qkv_w = (const float*)d_in[3];
    const float* qkv_b = (const float*)d_in[4];
    const float* out_w = (const float*)d_in[5];
    const float* out_b = (const float*)d_in[6];
    float* out = (float*)d_out;

    char* ws = (char*)d_ws;
    const size_t TOK = (size_t)B_ * N_;                 // 8192
    unsigned short* xn    = (unsigned short*)ws;  ws += TOK * DIM_ * 2;              // 8 MB
    unsigned short* wq_bf = (unsigned short*)ws;  ws += (size_t)3 * DIM_ * DIM_ * 2; // 1.5 MB
    unsigned short* wo_bf = (unsigned short*)ws;  ws += (size_t)DIM_ * DIM_ * 2;     // 0.5 MB
    unsigned short* Qh    = (unsigned short*)ws;  ws += TOK * DIM_ * 2;              // 8 MB
    unsigned short* Kh    = (unsigned short*)ws;  ws += TOK * DIM_ * 2;              // 8 MB
    unsigned short* Vt    = (unsigned short*)ws;  ws += TOK * DIM_ * 2;              // 8 MB
    unsigned short* Obuf  = (unsigned short*)ws;  ws += TOK * DIM_ * 2;              // 8 MB
    unsigned short* Opart = (unsigned short*)ws;  ws += (size_t)2 * TOK * DIM_ * 2;  // 16 MB
    float*          lpart = (float*)ws;           ws += (size_t)2 * B_ * NH_ * N_ * 4; // 0.5 MB

    const int NW = 3 * DIM_ * DIM_;      // qkv_w elements
    const int NO = DIM_ * DIM_;          // out_w elements

    ln_kernel<<<TOK, 256, 0, stream>>>(x, ln_w, ln_b, xn);
    cvt_kernel<<<(NW + NO + 255) / 256, 256, 0, stream>>>(qkv_w, NW, out_w, NO, wq_bf, wo_bf);
    qkv_gemm<<<dim3(TOK / 128, (3 * DIM_) / 128), 256, 0, stream>>>(xn, wq_bf, qkv_b, Qh, Kh, Vt);
    attn_kernel<<<dim3(N_ / 128, B_ * NH_, 2), 256, 0, stream>>>(Qh, Kh, Vt, Opart, lpart);
    combine_kernel<<<(TOK * DIM_) / 4 / 256, 256, 0, stream>>>(Opart, lpart, Obuf);
    out_gemm<<<dim3(TOK / 128, DIM_ / 128), 256, 0, stream>>>(Obuf, wo_bf, out_b, out);
}

// Round 9
// 183.041 us; speedup vs baseline: 2.1574x; 1.0402x over previous
//
#include <hip/hip_runtime.h>

typedef __attribute__((ext_vector_type(8))) short bf16x8;
typedef __attribute__((ext_vector_type(4))) float floatx4;

#define B_    4
#define N_    2048
#define DIM_  512
#define NH_   8
#define HD_   64
#define SCALE_ 0.125f
#define SL2E_ (0.125f * 1.44269504f)   // scale * log2(e), folded into Q

__device__ __forceinline__ unsigned short f32_to_bf16(float f) {
    unsigned int u = __float_as_uint(f);
    u += 0x7FFFu + ((u >> 16) & 1u);   // round-to-nearest-even
    return (unsigned short)(u >> 16);
}

__device__ __forceinline__ float bf16_to_f32(unsigned short u) {
    return __uint_as_float(((unsigned int)u) << 16);
}

__device__ __forceinline__ floatx4 mfma16(bf16x8 a, bf16x8 b, floatx4 c) {
    return __builtin_amdgcn_mfma_f32_16x16x32_bf16(a, b, c, 0, 0, 0);
}

__device__ __forceinline__ floatx4 fzero4() {
    floatx4 z = {0.f, 0.f, 0.f, 0.f};
    return z;
}

// async global->LDS DMA, 16B per lane. lds dest is wave-uniform base; HW adds lane*16.
__device__ __forceinline__ void async16(const unsigned short* g, unsigned short* l) {
    __builtin_amdgcn_global_load_lds((const __attribute__((address_space(1))) void*)g,
                                     (__attribute__((address_space(3))) void*)l,
                                     16, 0, 0);
}

// ---------------- LayerNorm: x[8192][512] fp32 -> xn bf16 ----------------
__global__ __launch_bounds__(256) void ln_kernel(const float* __restrict__ x,
                                                 const float* __restrict__ w,
                                                 const float* __restrict__ b,
                                                 unsigned short* __restrict__ xn) {
    int row = blockIdx.x;
    int tid = threadIdx.x;
    int lane = tid & 63, wid = tid >> 6;
    const float2 v = ((const float2*)(x + (size_t)row * DIM_))[tid];
    float s = v.x + v.y;
    float sq = v.x * v.x + v.y * v.y;
#pragma unroll
    for (int off = 1; off < 64; off <<= 1) {
        s  += __shfl_xor(s, off, 64);
        sq += __shfl_xor(sq, off, 64);
    }
    __shared__ float red[2][4];
    if (lane == 0) { red[0][wid] = s; red[1][wid] = sq; }
    __syncthreads();
    s  = red[0][0] + red[0][1] + red[0][2] + red[0][3];
    sq = red[1][0] + red[1][1] + red[1][2] + red[1][3];
    float mu   = s * (1.f / DIM_);
    float var  = sq * (1.f / DIM_) - mu * mu;
    float rstd = rsqrtf(var + 1e-5f);
    float2 wv = ((const float2*)w)[tid];
    float2 bv = ((const float2*)b)[tid];
    float y0 = (v.x - mu) * rstd * wv.x + bv.x;
    float y1 = (v.y - mu) * rstd * wv.y + bv.y;
    unsigned int pack = (unsigned int)f32_to_bf16(y0) |
                        ((unsigned int)f32_to_bf16(y1) << 16);
    ((unsigned int*)xn)[(size_t)row * (DIM_ / 2) + tid] = pack;
}

// ---------------- fp32 -> bf16 convert (both weight matrices, one launch) ----------------
__global__ __launch_bounds__(256) void cvt_kernel(const float* __restrict__ srcA, int na,
                                                  const float* __restrict__ srcB, int nb,
                                                  unsigned short* __restrict__ dstA,
                                                  unsigned short* __restrict__ dstB) {
    int idx = blockIdx.x * 256 + threadIdx.x;
    if (idx < na)            dstA[idx] = f32_to_bf16(srcA[idx]);
    else if (idx < na + nb)  dstB[idx - na] = f32_to_bf16(srcB[idx - na]);
}

// ================= m97-style LDS-staged GEMM core (shared by both GEMMs) =================
#define GEMM_CORE(A_, B_ptr, am0, bn0)                                              \
    __shared__ unsigned short Alds[2][128][32];                                     \
    __shared__ unsigned short Blds[2][128][32];                                     \
    int tid = threadIdx.x, lane = tid & 63, wid = tid >> 6;                         \
    int l15 = lane & 15, quad = lane >> 4;                                          \
    int wmloc = (wid >> 1) * 64, wnloc = (wid & 1) * 64;                            \
    int sr = lane >> 2;                                                             \
    int sc = (lane & 3) * 8;                                                        \
    floatx4 acc[4][4];                                                              \
    _Pragma("unroll")                                                               \
    for (int i = 0; i < 4; i++)                                                     \
        _Pragma("unroll")                                                           \
        for (int j = 0; j < 4; j++) acc[i][j] = fzero4();                           \
    int buf = 0;                                                                    \
    _Pragma("unroll")                                                               \
    for (int i = 0; i < 2; i++) {                                                   \
        int r0 = 32 * wid + 16 * i;                                                 \
        async16(A_ + (size_t)(am0 + r0 + sr) * DIM_ + sc, &Alds[0][r0][0]);         \
        async16(B_ptr + (size_t)(bn0 + r0 + sr) * DIM_ + sc, &Blds[0][r0][0]);      \
    }                                                                               \
    __syncthreads();                                                                \
    for (int t = 0; t < 16; t++) {                                                  \
        if (t < 15) {                                                               \
            int k0 = (t + 1) * 32;                                                  \
            _Pragma("unroll")                                                       \
            for (int i = 0; i < 2; i++) {                                           \
                int r0 = 32 * wid + 16 * i;                                         \
                async16(A_ + (size_t)(am0 + r0 + sr) * DIM_ + k0 + sc,              \
                        &Alds[buf ^ 1][r0][0]);                                     \
                async16(B_ptr + (size_t)(bn0 + r0 + sr) * DIM_ + k0 + sc,           \
                        &Blds[buf ^ 1][r0][0]);                                     \
            }                                                                       \
        }                                                                           \
        bf16x8 av[4], bv[4];                                                        \
        _Pragma("unroll")                                                           \
        for (int i = 0; i < 4; i++)                                                 \
            av[i] = *(const bf16x8*)(&Alds[buf][wmloc + 16 * i + l15][quad * 8]);   \
        _Pragma("unroll")                                                           \
        for (int j = 0; j < 4; j++)                                                 \
            bv[j] = *(const bf16x8*)(&Blds[buf][wnloc + 16 * j + l15][quad * 8]);   \
        _Pragma("unroll")                                                           \
        for (int i = 0; i < 4; i++)                                                 \
            _Pragma("unroll")                                                       \
            for (int j = 0; j < 4; j++)                                             \
                acc[i][j] = mfma16(av[i], bv[j], acc[i][j]);                        \
        __syncthreads();                                                            \
        buf ^= 1;                                                                   \
    }

// ---------------- QKV GEMM: [8192,512] x [1536,512]^T, scatter epilogue ----------------
// Q/K written [t][d] (32B-run stores, ok). V-blocks (bn0>=1024) transpose the
// wave tile through LDS (reusing Alds as scratch) and write Vt[d][t] as fully
// coalesced b128 stores -- the per-element b16 scatter (64 lines/inst) was the
// dominant cost of this kernel.
__global__ __launch_bounds__(256, 4) void qkv_gemm(const unsigned short* __restrict__ A,
                                                   const unsigned short* __restrict__ Bw,
                                                   const float* __restrict__ bias,
                                                   unsigned short* __restrict__ Qh,
                                                   unsigned short* __restrict__ Kh,
                                                   unsigned short* __restrict__ Vt) {
    int am0 = blockIdx.x * 128, bn0 = blockIdx.y * 128;
    GEMM_CORE(A, Bw, am0, bn0)

    if (bn0 >= 1024) {
        // ---- V path: LDS transpose -> coalesced Vt[d][t] writes ----
        unsigned short* sc_ = &Alds[0][0][0] + wid * (16 * 68);  // 1088 shorts/wave
        int m0 = am0 + wmloc;
        int bidx = m0 >> 11;
        int t0 = m0 & 2047;
#pragma unroll
        for (int j = 0; j < 4; j++) {
            float bias_n = bias[bn0 + wnloc + 16 * j + l15];
            // scratch[n_local 16][m_local 64], n_local = l15
#pragma unroll
            for (int i = 0; i < 4; i++)
#pragma unroll
                for (int r = 0; r < 4; r++)
                    sc_[l15 * 68 + 16 * i + quad * 4 + r] =
                        f32_to_bf16(acc[i][j][r] + bias_n);
            // wave-private scratch: compiler-ordered ds_write->ds_read, no barrier
#pragma unroll
            for (int half = 0; half < 2; half++) {
                int nr = 8 * half + (lane >> 3);
                int rem = (bn0 - 1024) + wnloc + 16 * j + nr;
                int head = rem >> 6, d = rem & 63;
                bf16x8 vv = *(const bf16x8*)(sc_ + nr * 68 + (lane & 7) * 8);
                *(bf16x8*)(Vt + ((size_t)(bidx * NH_ + head) * HD_ + d) * N_ +
                           t0 + (lane & 7) * 8) = vv;
            }
        }
    } else {
        // ---- Q/K path (32B-run b16 stores) ----
#pragma unroll
        for (int i = 0; i < 4; i++) {
#pragma unroll
            for (int j = 0; j < 4; j++) {
                int n = bn0 + wnloc + 16 * j + l15;
                float bias_n = bias[n];
                int which = n >> 9;
                int rem = n & 511;
                int head = rem >> 6;
                int d = rem & 63;
#pragma unroll
                for (int r = 0; r < 4; r++) {
                    int m = am0 + wmloc + 16 * i + quad * 4 + r;
                    int b = m >> 11;
                    int t = m & 2047;
                    float val = acc[i][j][r] + bias_n;
                    if (which == 0) {
                        Qh[((size_t)(b * NH_ + head) * N_ + t) * HD_ + d] =
                            f32_to_bf16(val * SL2E_);
                    } else {
                        Kh[((size_t)(b * NH_ + head) * N_ + t) * HD_ + d] =
                            f32_to_bf16(val);
                    }
                }
            }
        }
    }
}

// ---------------- Out projection: [8192,512] x [512,512]^T + bias -> fp32 ----------------
__global__ __launch_bounds__(256, 4) void out_gemm(const unsigned short* __restrict__ A,
                                                   const unsigned short* __restrict__ Bw,
                                                   const float* __restrict__ bias,
                                                   float* __restrict__ out) {
    int am0 = blockIdx.x * 128, bn0 = blockIdx.y * 128;
    GEMM_CORE(A, Bw, am0, bn0)

#pragma unroll
    for (int i = 0; i < 4; i++) {
#pragma unroll
        for (int j = 0; j < 4; j++) {
            int n = bn0 + wnloc + 16 * j + l15;
            float bias_n = bias[n];
#pragma unroll
            for (int r = 0; r < 4; r++) {
                int m = am0 + wmloc + 16 * i + quad * 4 + r;
                out[(size_t)m * DIM_ + n] = acc[i][j][r] + bias_n;
            }
        }
    }
}

// ---------------- Flash attention, fixed-max softmax, split-KV x2 ----------------
// (unchanged from R8: 71.4 us)
__global__ __launch_bounds__(256, 4) void attn_kernel(const unsigned short* __restrict__ Qh,
                                                      const unsigned short* __restrict__ Kh,
                                                      const unsigned short* __restrict__ Vtg,
                                                      unsigned short* __restrict__ Opart,
                                                      float* __restrict__ lpart) {
    int bh = blockIdx.y;
    int b = bh >> 3, head = bh & 7;
    int qt = blockIdx.x;
    int split = blockIdx.z;
    int kv0 = split << 10;                 // 0 or 1024
    int tid = threadIdx.x, lane = tid & 63, w = tid >> 6;
    int l15 = lane & 15, quad = lane >> 4;

    const unsigned short* Qp = Qh + (size_t)bh * N_ * HD_;
    const unsigned short* Kg = Kh + (size_t)bh * N_ * HD_;
    const unsigned short* Vg = Vtg + (size_t)bh * HD_ * N_;

    int q0 = qt * 128 + w * 32;

    bf16x8 aQ[2][2];
#pragma unroll
    for (int mh = 0; mh < 2; mh++) {
        const unsigned short* qrow = Qp + (size_t)(q0 + mh * 16 + l15) * HD_ + quad * 8;
        aQ[mh][0] = *(const bf16x8*)(qrow);
        aQ[mh][1] = *(const bf16x8*)(qrow + 32);
    }

    floatx4 of[2][4];
#pragma unroll
    for (int mh = 0; mh < 2; mh++)
#pragma unroll
        for (int t = 0; t < 4; t++) of[mh][t] = fzero4();
    floatx4 lacc[2];
    lacc[0] = fzero4(); lacc[1] = fzero4();

    const short onebf = (short)0x3F80;   // bf16 1.0
    bf16x8 ones = {onebf, onebf, onebf, onebf, onebf, onebf, onebf, onebf};

    __shared__ unsigned short Kt[64][64];      // 8 KB, XOR-swizzled, single-buffered
    __shared__ unsigned short Vs[64][64];      // 8 KB
    __shared__ unsigned short Pl[4][32][72];   // 18 KB, wave-private, padded

    int srow = lane >> 3;                 // 0..7
    int scol = ((lane & 7) ^ srow) * 8;   // shorts

    int swz0 = (quad ^ (l15 & 7)) * 8;
    int swz1 = ((quad + 4) ^ (l15 & 7)) * 8;

    unsigned short* myP = &Pl[w][0][0];
    for (int kv = kv0; kv < kv0 + 1024; kv += 64) {
#pragma unroll
        for (int i = 0; i < 2; i++) {
            int r0 = 16 * w + 8 * i;
            async16(Kg + (size_t)(kv + r0 + srow) * HD_ + scol, &Kt[r0][0]);
            async16(Vg + (size_t)(r0 + srow) * N_ + kv + scol, &Vs[r0][0]);
        }
        __syncthreads();
        bf16x8 kf[8];
#pragma unroll
        for (int h = 0; h < 4; h++) {
            kf[2 * h]     = *(const bf16x8*)(&Kt[16 * h + l15][swz0]);
            kf[2 * h + 1] = *(const bf16x8*)(&Kt[16 * h + l15][swz1]);
        }
#pragma unroll
        for (int mh = 0; mh < 2; mh++) {
            floatx4 c[4];
#pragma unroll
            for (int h = 0; h < 4; h++) {
                floatx4 cc = fzero4();
                cc = mfma16(aQ[mh][0], kf[2 * h], cc);
                cc = mfma16(aQ[mh][1], kf[2 * h + 1], cc);
                c[h] = cc;
            }
            unsigned short* pw = myP + (mh * 16 + quad * 4) * 72 + l15;
#pragma unroll
            for (int h = 0; h < 4; h++)
#pragma unroll
                for (int r = 0; r < 4; r++)
                    pw[r * 72 + h * 16] = f32_to_bf16(exp2f(c[h][r]));
        }
        bf16x8 vf[8];
#pragma unroll
        for (int t = 0; t < 4; t++) {
            vf[2 * t]     = *(const bf16x8*)(&Vs[16 * t + l15][swz0]);
            vf[2 * t + 1] = *(const bf16x8*)(&Vs[16 * t + l15][swz1]);
        }
#pragma unroll
        for (int mh = 0; mh < 2; mh++) {
            const unsigned short* pr = myP + (mh * 16 + l15) * 72;
            bf16x8 aP0 = *(const bf16x8*)(pr + quad * 8);
            bf16x8 aP1 = *(const bf16x8*)(pr + 32 + quad * 8);
#pragma unroll
            for (int t = 0; t < 4; t++) {
                of[mh][t] = mfma16(aP0, vf[2 * t], of[mh][t]);
                of[mh][t] = mfma16(aP1, vf[2 * t + 1], of[mh][t]);
            }
            lacc[mh] = mfma16(aP0, ones, lacc[mh]);
            lacc[mh] = mfma16(aP1, ones, lacc[mh]);
        }
        __syncthreads();
    }

    unsigned short* Od = Opart + (size_t)split * B_ * N_ * DIM_;
#pragma unroll
    for (int mh = 0; mh < 2; mh++) {
        float inv[4];
#pragma unroll
        for (int r = 0; r < 4; r++) inv[r] = 1.f / lacc[mh][r];
#pragma unroll
        for (int t = 0; t < 4; t++) {
#pragma unroll
            for (int r = 0; r < 4; r++) {
                int t_tok = q0 + mh * 16 + quad * 4 + r;
                int d = 16 * t + l15;
                Od[((size_t)b * N_ + t_tok) * DIM_ + head * HD_ + d] =
                    f32_to_bf16(of[mh][t][r] * inv[r]);
            }
        }
        if (l15 == 0) {
#pragma unroll
            for (int r = 0; r < 4; r++) {
                int t_tok = q0 + mh * 16 + quad * 4 + r;
                lpart[(size_t)split * B_ * NH_ * N_ + (size_t)bh * N_ + t_tok] =
                    lacc[mh][r];
            }
        }
    }
}

// ---------------- combine: Obuf = (l1*O1 + l2*O2)/(l1+l2), bf16 ----------------
__global__ __launch_bounds__(256) void combine_kernel(const unsigned short* __restrict__ Opart,
                                                      const float* __restrict__ lpart,
                                                      unsigned short* __restrict__ Obuf) {
    int idx = blockIdx.x * 256 + threadIdx.x;   // 4-element groups
    int row = idx >> 7;
    int head = (idx & 127) >> 4;
    int b = row >> 11, t = row & 2047;
    size_t li = (size_t)(b * NH_ + head) * N_ + t;
    float l1 = lpart[li];
    float l2 = lpart[(size_t)B_ * NH_ * N_ + li];
    float s = 1.f / (l1 + l2);
    float w1 = l1 * s, w2 = l2 * s;
    const size_t half = (size_t)B_ * N_ * DIM_;
    ushort4 a = ((const ushort4*)Opart)[idx];
    ushort4 c = ((const ushort4*)(Opart + half))[idx];
    ushort4 o;
    o.x = f32_to_bf16(w1 * bf16_to_f32(a.x) + w2 * bf16_to_f32(c.x));
    o.y = f32_to_bf16(w1 * bf16_to_f32(a.y) + w2 * bf16_to_f32(c.y));
    o.z = f32_to_bf16(w1 * bf16_to_f32(a.z) + w2 * bf16_to_f32(c.z));
    o.w = f32_to_bf16(w1 * bf16_to_f32(a.w) + w2 * bf16_to_f32(c.w));
    ((ushort4*)Obuf)[idx] = o;
}

extern "C" void kernel_launch(void* const* d_in, const int* in_sizes, int n_in,
                              void* d_out, int out_size, void* d_ws, size_t ws_size,
                              hipStream_t stream) {
    const float* x     = (const float*)d_in[0];
    const float* ln_w  = (const float*)d_in[1];
    const float* ln_b  = (const float*)d_in[2];
    const float* qkv_w = (const float*)d_in[3];
    const float* qkv_b = (const float*)d_in[4];
    const float* out_w = (const float*)d_in[5];
    const float* out_b = (const float*)d_in[6];
    float* out = (float*)d_out;

    char* ws = (char*)d_ws;
    const size_t TOK = (size_t)B_ * N_;                 // 8192
    unsigned short* xn    = (unsigned short*)ws;  ws += TOK * DIM_ * 2;
    unsigned short* wq_bf = (unsigned short*)ws;  ws += (size_t)3 * DIM_ * DIM_ * 2;
    unsigned short* wo_bf = (unsigned short*)ws;  ws += (size_t)DIM_ * DIM_ * 2;
    unsigned short* Qh    = (unsigned short*)ws;  ws += TOK * DIM_ * 2;
    unsigned short* Kh    = (unsigned short*)ws;  ws += TOK * DIM_ * 2;
    unsigned short* Vt    = (unsigned short*)ws;  ws += TOK * DIM_ * 2;
    unsigned short* Obuf  = (unsigned short*)ws;  ws += TOK * DIM_ * 2;
    unsigned short* Opart = (unsigned short*)ws;  ws += (size_t)2 * TOK * DIM_ * 2;
    float*          lpart = (float*)ws;           ws += (size_t)2 * B_ * NH_ * N_ * 4;

    const int NW = 3 * DIM_ * DIM_;
    const int NO = DIM_ * DIM_;

    ln_kernel<<<TOK, 256, 0, stream>>>(x, ln_w, ln_b, xn);
    cvt_kernel<<<(NW + NO + 255) / 256, 256, 0, stream>>>(qkv_w, NW, out_w, NO, wq_bf, wo_bf);
    qkv_gemm<<<dim3(TOK / 128, (3 * DIM_) / 128), 256, 0, stream>>>(xn, wq_bf, qkv_b, Qh, Kh, Vt);
    attn_kernel<<<dim3(N_ / 128, B_ * NH_, 2), 256, 0, stream>>>(Qh, Kh, Vt, Opart, lpart);
    combine_kernel<<<(TOK * DIM_) / 4 / 256, 256, 0, stream>>>(Opart, lpart, Obuf);
    out_gemm<<<dim3(TOK / 128, DIM_ / 128), 256, 0, stream>>>(Obuf, wo_bf, out_b, out);
}